// Round 11
// baseline (748.386 us; speedup 1.0000x reference)
//
#include <hip/hip_runtime.h>
#include <hip/hip_bf16.h>
#include <stdint.h>

// ---------------------------------------------------------------------------
// HConstructor: slot-attention-like block on MI355X.
//   inputs [65536,256], noise [1024,256] -> edges [1024,256], H [65536,1024],
//   dots2 [65536,1024].
// Pipeline (all on `stream`):
//   prep_w   : Wcat^T = [wk|wv|wq]^T as bf16 [768,256], bias cat
//   edges_e  : edges = mu + exp(ls)*noise ; e = LN(edges)  (f32 + bf16)
//   ln_x     : x = LN(inputs) -> bf16 [65536,256]
//   gemm<1>  : q  = relu(e @ wq + bq)           [1024,256]  bf16
//   gemm<0>  : k,v = relu(x@wk/v + b) -> H-region; q2 strided into dots2 rows
//   gemm<2>  : dots = (q @ k^T) * 1/16 -> bf16 [1024,65536] (H-region scratch)
//   d2d3 v2  : 3-pass streaming rank-select, ~27 KB LDS, all 1024 blocks
//              co-resident (unchanged from R10).
//   mlp      : edges_out = relu([e,upd]@w1+b1)@w2+b2 -> OUT + bf16
//   gemm<1>  : k2 = relu(edges_out @ wk + bk) -> d_ws (512 KB)
//   d3h v5   : FUSED dots2 + H with NO main-loop barriers.  Every prior d3h
//              (R7 global round-trip, R8 1-blk/CU LDS tile, R9/R10 dbuf Bk)
//              died on barrier-locked fine staging: global->LDS stage exposes
//              L2 latency before 2 MFMAs of work, 64x per block.  v5 loads
//              MFMA B-operands global->VGPR DIRECTLY (k2 = 512 KB, L2-hot;
//              fragment = 16 rows x 64 B segments) -- no Bk, no barriers;
//              16 independent waves/CU hide latency.  LDS = bf16 keys only
//              (64 KB, 2 blk/CU).  Final phase (unchanged): per-wave dots2
//              f32 write + softmax + 16-step top-ke from keys -> H.
// Scratch map:
//   H region   : dots(134M) | xln(32M) | kb(32M) | vb(32M) | smalls(~4M)
//   dots2 reg. : q2-strided tiles (consumed block-locally by d3h)
//   d_ws       : k2 bf16 (512 KB)
// ---------------------------------------------------------------------------

#define DEV __device__ __forceinline__

typedef uint32_t u32;
typedef uint16_t u16;
typedef __bf16 v8bf __attribute__((ext_vector_type(8)));
typedef float v4f __attribute__((ext_vector_type(4)));

static constexpr long NN = 65536;
static constexpr long DD = 256;
static constexpr long NSL = 1024;

DEV u16 f2b(float f) {
  u32 u = __builtin_bit_cast(u32, f);
  u32 r = (u + 0x7FFFu + ((u >> 16) & 1u)) >> 16;
  return (u16)r;
}
DEV float b2f(u16 h) { u32 u = ((u32)h) << 16; return __builtin_bit_cast(float, u); }
// bf16 bits (as u32 low16) -> monotone sortable 16-bit key
DEV u32 b2k(u32 b) { return b ^ (0x8000u + 0x7FFFu * (b >> 15)); }
DEV float k2fv(u32 k) {
  u16 b = (k & 0x8000u) ? (u16)(k ^ 0x8000u) : (u16)(k ^ 0xFFFFu);
  return b2f(b);
}

// ---------------------------------------------------------------------------
// Generic  C[M,N] = epilogue(A[M,256] @ B[N,256]^T)   (bf16 in, MFMA 16x16x32)
// 128x128 tile, BK=64, 4 waves (2x2), XOR-swizzled LDS (16B chunk ^ row&7).
// EPI 0: +biascat, relu for cols<512, route {0:k,1:v,2:q2-strided} bf16
// EPI 1: +bias, relu, bf16 out [M,256]
// EPI 2: *scale, bf16 out ld=65536
// ---------------------------------------------------------------------------
template <int EPI>
__global__ __launch_bounds__(256, 2)
void gemm_bt(const u16* __restrict__ A, const u16* __restrict__ B,
             const float* __restrict__ bias, float scale,
             u16* __restrict__ ob0, u16* __restrict__ ob1, u16* __restrict__ ob2,
             float* __restrict__ of) {
  __shared__ __align__(16) u16 As[128 * 64];
  __shared__ __align__(16) u16 Bs[128 * 64];
  const int tid = threadIdx.x;
  const int lane = tid & 63;
  const int l15 = lane & 15;
  const int l4 = lane >> 4;
  const int wid = tid >> 6;
  const int wm = wid >> 1, wn = wid & 1;
  const long m0 = (long)blockIdx.y * 128;
  const long n0 = (long)blockIdx.x * 128;

  v4f acc[4][4] = {};

  for (int kb = 0; kb < 256; kb += 64) {
    __syncthreads();
#pragma unroll
    for (int i = 0; i < 4; i++) {
      int cid = tid + 256 * i;          // 1024 16B-chunks per tile
      int row = cid >> 3, ch = cid & 7; // 8 chunks per 64-col row
      int sch = ch ^ (row & 7);
      uint4 da = *reinterpret_cast<const uint4*>(A + (m0 + row) * 256 + kb + ch * 8);
      *reinterpret_cast<uint4*>(&As[row * 64 + sch * 8]) = da;
      uint4 db = *reinterpret_cast<const uint4*>(B + (n0 + row) * 256 + kb + ch * 8);
      *reinterpret_cast<uint4*>(&Bs[row * 64 + sch * 8]) = db;
    }
    __syncthreads();
#pragma unroll
    for (int ks = 0; ks < 2; ks++) {
      v8bf af[4], bfr[4];
#pragma unroll
      for (int m = 0; m < 4; m++) {
        int row = wm * 64 + m * 16 + l15;
        int sch = (ks * 4 + l4) ^ (row & 7);
        af[m] = *reinterpret_cast<const v8bf*>(&As[row * 64 + sch * 8]);
      }
#pragma unroll
      for (int n = 0; n < 4; n++) {
        int row = wn * 64 + n * 16 + l15;
        int sch = (ks * 4 + l4) ^ (row & 7);
        bfr[n] = *reinterpret_cast<const v8bf*>(&Bs[row * 64 + sch * 8]);
      }
#pragma unroll
      for (int m = 0; m < 4; m++)
#pragma unroll
        for (int n = 0; n < 4; n++)
          acc[m][n] = __builtin_amdgcn_mfma_f32_16x16x32_bf16(af[m], bfr[n], acc[m][n], 0, 0, 0);
    }
  }

  const int r4 = l4 * 4;
#pragma unroll
  for (int m = 0; m < 4; m++) {
#pragma unroll
    for (int n = 0; n < 4; n++) {
#pragma unroll
      for (int r = 0; r < 4; r++) {
        long grow = m0 + wm * 64 + m * 16 + r4 + r;
        long gcol = n0 + wn * 64 + n * 16 + l15;
        float v = acc[m][n][r];
        if constexpr (EPI == 0) {
          v += bias[gcol];
          int which = (int)(gcol >> 8);
          long jj = gcol & 255;
          if (which < 2) v = fmaxf(v, 0.f);
          u16 hv = f2b(v);
          if (which == 0) ob0[grow * 256 + jj] = hv;
          else if (which == 1) ob1[grow * 256 + jj] = hv;
          else ob2[(grow & ~31L) * 2048 + (grow & 31) * 256 + jj] = hv;  // q2 strided
        } else if constexpr (EPI == 1) {
          v += bias[gcol];
          v = fmaxf(v, 0.f);
          ob0[grow * 256 + gcol] = f2b(v);
        } else if constexpr (EPI == 2) {
          ob0[grow * 65536 + gcol] = f2b(v * scale);
        } else {
          of[grow * 1024 + gcol] = v * scale;
        }
      }
    }
  }
}

// ---------------------------------------------------------------------------
// Weight prep: Wcat^T bf16 [768,256] rows = [wk cols | wv cols | wq cols]
// ---------------------------------------------------------------------------
__global__ __launch_bounds__(256)
void prep_w_kernel(const float* __restrict__ wq, const float* __restrict__ wk,
                   const float* __restrict__ wv, const float* __restrict__ bq,
                   const float* __restrict__ bk, const float* __restrict__ bv,
                   u16* __restrict__ wcat, float* __restrict__ bcat) {
  int n = blockIdx.x;
  int t = threadIdx.x;
  const float* W = (n < 256) ? wk : (n < 512) ? wv : wq;
  int jj = n & 255;
  wcat[n * 256 + t] = f2b(W[t * 256 + jj]);
  if (t == 0) {
    const float* Bb = (n < 256) ? bk : (n < 512) ? bv : bq;
    bcat[n] = Bb[jj];
  }
}

// ---------------------------------------------------------------------------
// x = LayerNorm(inputs) -> bf16.  One wave per row (4 f32 per lane).
// ---------------------------------------------------------------------------
__global__ __launch_bounds__(256)
void ln_x_kernel(const float* __restrict__ x, const float* __restrict__ lw,
                 const float* __restrict__ lb, u16* __restrict__ out) {
  const int lane = threadIdx.x & 63, wid = threadIdx.x >> 6;
  const long row = (long)blockIdx.x * 4 + wid;
  float4 v = reinterpret_cast<const float4*>(x + row * 256)[lane];
  float s = v.x + v.y + v.z + v.w;
  for (int sh = 1; sh < 64; sh <<= 1) s += __shfl_xor(s, sh);
  float mu = s * (1.f / 256.f);
  float dx = v.x - mu, dy = v.y - mu, dz = v.z - mu, dw = v.w - mu;
  float q = dx * dx + dy * dy + dz * dz + dw * dw;
  for (int sh = 1; sh < 64; sh <<= 1) q += __shfl_xor(q, sh);
  float rs = rsqrtf(q * (1.f / 256.f) + 1e-5f);
  float4 wv = reinterpret_cast<const float4*>(lw)[lane];
  float4 bv = reinterpret_cast<const float4*>(lb)[lane];
  ushort4 o4;
  o4.x = f2b(dx * rs * wv.x + bv.x);
  o4.y = f2b(dy * rs * wv.y + bv.y);
  o4.z = f2b(dz * rs * wv.z + bv.z);
  o4.w = f2b(dw * rs * wv.w + bv.w);
  reinterpret_cast<ushort4*>(out + row * 256)[lane] = o4;
}

// ---------------------------------------------------------------------------
// edges = mu + exp(ls)*noise ; e = LayerNorm(edges) -> f32 + bf16
// ---------------------------------------------------------------------------
__global__ __launch_bounds__(256)
void edges_e_kernel(const float* __restrict__ noise, const float* __restrict__ emu,
                    const float* __restrict__ els, const float* __restrict__ lw,
                    const float* __restrict__ lb, float* __restrict__ e_f,
                    u16* __restrict__ e_b) {
  const int lane = threadIdx.x & 63, wid = threadIdx.x >> 6;
  const long row = (long)blockIdx.x * 4 + wid;
  float4 nz = reinterpret_cast<const float4*>(noise + row * 256)[lane];
  float4 mu4 = reinterpret_cast<const float4*>(emu)[lane];
  float4 ls4 = reinterpret_cast<const float4*>(els)[lane];
  float4 ed;
  ed.x = mu4.x + expf(ls4.x) * nz.x;
  ed.y = mu4.y + expf(ls4.y) * nz.y;
  ed.z = mu4.z + expf(ls4.z) * nz.z;
  ed.w = mu4.w + expf(ls4.w) * nz.w;
  float s = ed.x + ed.y + ed.z + ed.w;
  for (int sh = 1; sh < 64; sh <<= 1) s += __shfl_xor(s, sh);
  float mu = s * (1.f / 256.f);
  float dx = ed.x - mu, dy = ed.y - mu, dz = ed.z - mu, dw = ed.w - mu;
  float qv = dx * dx + dy * dy + dz * dz + dw * dw;
  for (int sh = 1; sh < 64; sh <<= 1) qv += __shfl_xor(qv, sh);
  float rs = rsqrtf(qv * (1.f / 256.f) + 1e-5f);
  float4 wv = reinterpret_cast<const float4*>(lw)[lane];
  float4 bv = reinterpret_cast<const float4*>(lb)[lane];
  float4 ef;
  ef.x = dx * rs * wv.x + bv.x;
  ef.y = dy * rs * wv.y + bv.y;
  ef.z = dz * rs * wv.z + bv.z;
  ef.w = dw * rs * wv.w + bv.w;
  reinterpret_cast<float4*>(e_f + row * 256)[lane] = ef;
  ushort4 o4;
  o4.x = f2b(ef.x); o4.y = f2b(ef.y); o4.z = f2b(ef.z); o4.w = f2b(ef.w);
  reinterpret_cast<ushort4*>(e_b + row * 256)[lane] = o4;
}

// ---------------------------------------------------------------------------
// d2d3 v2 (unchanged from R10): one block (256 threads) per q-row, ~27 KB
// LDS, all 1024 blocks co-resident.  3-pass streaming histogram rank-select
// + sparse attn@v gather.  Fixed softmax shift C=8.
// ---------------------------------------------------------------------------
struct D2Shm {
  u32 hist[256 * 16];     // 16 KiB: bin b, copy c at [b*16+c]
  u32 c_hi[256];
  u32 sel_idx[1152];
  float sel_w[1152];
  float fred[4];
  u32 sb_star, sThi, sThr;
  float sSE, sFrac;
  u32 scnt;
};

__global__ __launch_bounds__(256, 5)
void d2d3_kernel(const u16* __restrict__ dots, const u16* __restrict__ vmat,
                 const int* __restrict__ knp, float* __restrict__ upd) {
  __shared__ D2Shm S;
  const int tid = threadIdx.x, lane = tid & 63, wid = tid >> 6;
  const int hc = (lane >> 2);          // 16 lane-indexed histogram copies
  const long r = blockIdx.x;
  const int kn = *knp;

  for (int i = tid; i < 4096; i += 256) S.hist[i] = 0;
  if (tid == 0) S.scnt = 0;
  __syncthreads();

  const float C = 8.f;  // fixed softmax shift (dots >= 0 since q,k relu'd)
  const uint4* src = reinterpret_cast<const uint4*>(dots + r * 65536);

  // ---- pass 1: high-byte histogram + sum-exp ----
  float se = 0.f;
  for (int c = tid; c < 8192; c += 256) {
    uint4 d = src[c];
    u32 h[8] = {d.x & 0xffffu, d.x >> 16, d.y & 0xffffu, d.y >> 16,
                d.z & 0xffffu, d.z >> 16, d.w & 0xffffu, d.w >> 16};
#pragma unroll
    for (int j = 0; j < 8; j++) {
      u32 k = b2k(h[j]);
      se += __expf(b2f((u16)h[j]) - C);
      atomicAdd(&S.hist[(k >> 8) * 16 + hc], 1u);
    }
  }
  for (int sh = 1; sh < 64; sh <<= 1) se += __shfl_xor(se, sh);
  if (lane == 0) S.fred[wid] = se;
  __syncthreads();

  // reduce copies -> c_hi
  {
    u32 s = 0;
#pragma unroll
    for (int c = 0; c < 16; c++) s += S.hist[tid * 16 + c];
    S.c_hi[tid] = s;
  }
  __syncthreads();

  // ---- scan 1: wave 0 -> b*, Thi;  waves 1-3 re-zero hist ----
  if (tid < 64) {
    u32 s = S.c_hi[4 * tid] + S.c_hi[4 * tid + 1] + S.c_hi[4 * tid + 2] + S.c_hi[4 * tid + 3];
    u32 v = s;
    for (int off = 1; off < 64; off <<= 1) {
      u32 t = (u32)__shfl_down((int)v, off);
      if (tid + off < 64) v += t;        // inclusive suffix sum over lanes
    }
    u32 excl = v - s;
    if (v >= (u32)kn && excl < (u32)kn) {
      u32 acc = excl;
#pragma unroll
      for (int bb = 3; bb >= 0; --bb) {
        int b = 4 * tid + bb;
        u32 nb = acc + S.c_hi[b];
        if (nb >= (u32)kn) { S.sb_star = (u32)b; S.sThi = acc; break; }
        acc = nb;
      }
    }
  } else {
    for (int i = tid - 64; i < 4096; i += 192) S.hist[i] = 0;
  }
  __syncthreads();
  const u32 bstar = S.sb_star;

  // ---- pass 2: low-byte histogram within bin b* (row re-read, L3-hot) ----
  for (int c = tid; c < 8192; c += 256) {
    uint4 d = src[c];
    u32 h[8] = {d.x & 0xffffu, d.x >> 16, d.y & 0xffffu, d.y >> 16,
                d.z & 0xffffu, d.z >> 16, d.w & 0xffffu, d.w >> 16};
#pragma unroll
    for (int j = 0; j < 8; j++) {
      u32 k = b2k(h[j]);
      if ((k >> 8) == bstar) atomicAdd(&S.hist[(k & 255u) * 16 + hc], 1u);
    }
  }
  __syncthreads();
  {
    u32 s = 0;
#pragma unroll
    for (int c = 0; c < 16; c++) s += S.hist[tid * 16 + c];
    S.c_hi[tid] = s;
  }
  __syncthreads();

  // ---- scan 2: wave 0 -> exact threshold, tie counts, SE ----
  if (tid < 64) {
    u32 s = S.c_hi[4 * tid] + S.c_hi[4 * tid + 1] + S.c_hi[4 * tid + 2] + S.c_hi[4 * tid + 3];
    u32 v = s;
    for (int off = 1; off < 64; off <<= 1) {
      u32 t = (u32)__shfl_down((int)v, off);
      if (tid + off < 64) v += t;
    }
    const u32 Thi = S.sThi;              // count(high byte > b*)
    u32 incl = v + Thi;
    u32 excl = v - s + Thi;
    if (incl >= (u32)kn && excl < (u32)kn) {
      u32 acc = excl;
#pragma unroll
      for (int bb = 3; bb >= 0; --bb) {
        int b = 4 * tid + bb;
        u32 nb = acc + S.c_hi[b];
        if (nb >= (u32)kn) {
          S.sThr = (bstar << 8) | (u32)b;
          // acc = count(key > thr), c_hi[b] = count(key == thr)
          S.sFrac = (float)(int)((u32)kn - acc) / (float)S.c_hi[b];
          break;
        }
        acc = nb;
      }
    }
    if (tid == 0) {
      float SE = S.fred[0] + S.fred[1] + S.fred[2] + S.fred[3];
      S.sSE = SE;
    }
  }
  __syncthreads();
  const u32 thr = S.sThr;
  const float frac = S.sFrac;
  const float invs = 1.f / S.sSE;
  const float wnorm = 1.f / (1.f + 65536.f * 1e-8f);

  // ---- pass 3: selection: keys >= thr -> (global idx, weight) list ----
  for (int c = tid; c < 8192; c += 256) {
    uint4 d = src[c];
    u32 h[8] = {d.x & 0xffffu, d.x >> 16, d.y & 0xffffu, d.y >> 16,
                d.z & 0xffffu, d.z >> 16, d.w & 0xffffu, d.w >> 16};
#pragma unroll
    for (int j = 0; j < 8; j++) {
      u32 k = b2k(h[j]);
      if (k >= thr) {
        float w = (__expf(k2fv(k) - C) * invs + 1e-8f) * wnorm;
        if (k == thr) w *= frac;
        u32 p = atomicAdd(&S.scnt, 1u);
        if (p < 1152u) { S.sel_idx[p] = (u32)c * 8u + (u32)j; S.sel_w[p] = w; }
      }
    }
  }
  __syncthreads();
  const u32 nsel = S.scnt < 1152u ? S.scnt : 1152u;

  // ---- gather: thread t owns output col t; 4-deep ILP ----
  float a0 = 0.f, a1 = 0.f, a2 = 0.f, a3 = 0.f;
  u32 j = 0;
  for (; j + 3 < nsel; j += 4) {
    a0 = fmaf(S.sel_w[j], b2f(vmat[(long)S.sel_idx[j] * 256 + tid]), a0);
    a1 = fmaf(S.sel_w[j + 1], b2f(vmat[(long)S.sel_idx[j + 1] * 256 + tid]), a1);
    a2 = fmaf(S.sel_w[j + 2], b2f(vmat[(long)S.sel_idx[j + 2] * 256 + tid]), a2);
    a3 = fmaf(S.sel_w[j + 3], b2f(vmat[(long)S.sel_idx[j + 3] * 256 + tid]), a3);
  }
  for (; j < nsel; ++j)
    a0 = fmaf(S.sel_w[j], b2f(vmat[(long)S.sel_idx[j] * 256 + tid]), a0);
  upd[r * 256 + tid] = (a0 + a1) + (a2 + a3);
}

// ---------------------------------------------------------------------------
// mlp: edges_out = relu([e, upd] @ w1 + b1) @ w2 + b2   (f32, one block/row)
// ---------------------------------------------------------------------------
__global__ __launch_bounds__(256)
void mlp_kernel(const float* __restrict__ e, const float* __restrict__ upd,
                const float* __restrict__ w1, const float* __restrict__ b1,
                const float* __restrict__ w2, const float* __restrict__ b2,
                float* __restrict__ eout, u16* __restrict__ eb) {
  __shared__ float ecat[512];
  __shared__ float h[256];
  const int t = threadIdx.x;
  const long r = blockIdx.x;
  ecat[t] = e[r * 256 + t];
  ecat[256 + t] = upd[r * 256 + t];
  __syncthreads();
  float acc = b1[t];
#pragma unroll 8
  for (int kk = 0; kk < 512; ++kk) acc = fmaf(ecat[kk], w1[kk * 256 + t], acc);
  h[t] = fmaxf(acc, 0.f);
  __syncthreads();
  float a2 = b2[t];
#pragma unroll 8
  for (int kk = 0; kk < 256; ++kk) a2 = fmaf(h[kk], w2[kk * 256 + t], a2);
  eout[r * 256 + t] = a2;
  eb[r * 256 + t] = f2b(a2);
}

// ---------------------------------------------------------------------------
// d3h v5: FUSED dots2 + H, NO main-loop barriers.  One block = 32 rows,
// 512 threads, 8 waves as 2M(16 rows) x 4N(256 cols each).
//   setup  : A(q2) fragments -> registers (8 v8bf/lane, one-time L2 read)
//   per nc : 16-col chunk: 8 global v8bf B-loads (k2 L2-resident) + 8 MFMA,
//            acc -> bf16 keys in LDS (own slots).  No LDS staging of B,
//            no __syncthreads -- 16 waves/CU run independently.
//   final  : one barrier; per-wave, 4 rows: dots2 f32 write (from keys) +
//            softmax + 16-step top-ke on monotone keys -> H.
// LDS = keys 64 KB only -> 2 blocks/CU.
// ---------------------------------------------------------------------------
struct D3HShm {
  u16 keys[32 * 1024];     // 64 KiB bf16 dots2 values
};

__global__ __launch_bounds__(512, 4)
void d3h_kernel(const u16* __restrict__ q2s, const u16* __restrict__ k2,
                const int* __restrict__ kep, float* __restrict__ d2out,
                float* __restrict__ H) {
  extern __shared__ char d3hsm[];
  D3HShm* S = reinterpret_cast<D3HShm*>(d3hsm);
  const int tid = threadIdx.x;
  const int lane = tid & 63;
  const int l15 = lane & 15;
  const int l4 = lane >> 4;
  const int w = tid >> 6;
  const int wm = w >> 2, wn = w & 3;
  const long m0 = (long)blockIdx.x * 32;

  // ---- A fragments into registers (one-time; q2 tile is 16 KB, L2-hot) ----
  const u16* q2blk = q2s + m0 * 2048;          // own strided slot
  const int arow = wm * 16 + l15;
  v8bf afrag[8];
#pragma unroll
  for (int kk = 0; kk < 8; kk++)
    afrag[kk] = *reinterpret_cast<const v8bf*>(q2blk + arow * 256 + kk * 32 + l4 * 8);

  // ---- main loop: 16 chunks of 16 cols; B direct from global (L2) ----
#pragma unroll 1
  for (int nc = 0; nc < 16; nc++) {
    const u16* kr = k2 + ((long)(wn * 256 + nc * 16 + l15)) * 256 + l4 * 8;
    v4f acc = {};
#pragma unroll
    for (int kk = 0; kk < 8; kk++) {
      v8bf b = *reinterpret_cast<const v8bf*>(kr + kk * 32);
      acc = __builtin_amdgcn_mfma_f32_16x16x32_bf16(afrag[kk], b, acc, 0, 0, 0);
    }
#pragma unroll
    for (int r = 0; r < 4; r++) {
      int lr = wm * 16 + l4 * 4 + r;           // 0..31
      S->keys[lr * 1024 + wn * 256 + nc * 16 + l15] = f2b(acc[r] * 0.0625f);
    }
  }
  __syncthreads();

  // ---- final: wave w owns rows m0 + w*4 .. +3; dots2 + softmax + top-ke ----
  const int ke = *kep;
#pragma unroll
  for (int j = 0; j < 4; j++) {
    const int lrow = w * 4 + j;
    const long row = m0 + lrow;
    uint4 ka = *reinterpret_cast<const uint4*>(&S->keys[lrow * 1024 + lane * 16]);
    uint4 kb2 = *reinterpret_cast<const uint4*>(&S->keys[lrow * 1024 + lane * 16 + 8]);
    u32 kw[8] = {ka.x, ka.y, ka.z, ka.w, kb2.x, kb2.y, kb2.z, kb2.w};
    u32 k16[16];
    float x[16];
#pragma unroll
    for (int i = 0; i < 8; i++) {
      u32 lo16 = kw[i] & 0xffffu, hi16 = kw[i] >> 16;
      k16[2 * i] = b2k(lo16);     x[2 * i] = b2f((u16)lo16);
      k16[2 * i + 1] = b2k(hi16); x[2 * i + 1] = b2f((u16)hi16);
    }
    // stream dots2 (f32 from bf16 values; <=0.5 ULP rounding)
    float4* ddst = reinterpret_cast<float4*>(&d2out[row * 1024 + lane * 16]);
#pragma unroll
    for (int i = 0; i < 4; i++) {
      float4 dv;
      dv.x = x[4 * i]; dv.y = x[4 * i + 1]; dv.z = x[4 * i + 2]; dv.w = x[4 * i + 3];
      ddst[i] = dv;
    }
    float mx = x[0];
#pragma unroll
    for (int i = 1; i < 16; i++) mx = fmaxf(mx, x[i]);
    for (int sh = 1; sh < 64; sh <<= 1) mx = fmaxf(mx, __shfl_xor(mx, sh));
    float p[16];
    float se = 0.f;
#pragma unroll
    for (int i = 0; i < 16; i++) { p[i] = __expf(x[i] - mx); se += p[i]; }
    for (int sh = 1; sh < 64; sh <<= 1) se += __shfl_xor(se, sh);
    const float invs = 1.f / se;
    u32 lo = 0;
    for (int b = 15; b >= 0; --b) {
      u32 t = lo | (1u << b);
      int cnt = 0;
#pragma unroll
      for (int i = 0; i < 16; i++) cnt += (k16[i] >= t);
      for (int sh = 1; sh < 64; sh <<= 1) cnt += __shfl_xor(cnt, sh);
      if (cnt >= ke) lo = t;
    }
    float o[16];
#pragma unroll
    for (int i = 0; i < 16; i++) o[i] = (k16[i] >= lo) ? p[i] * invs : 0.f;
    float4* dst = reinterpret_cast<float4*>(&H[row * 1024 + lane * 16]);
#pragma unroll
    for (int i = 0; i < 4; i++) {
      float4 ov;
      ov.x = o[4 * i]; ov.y = o[4 * i + 1]; ov.z = o[4 * i + 2]; ov.w = o[4 * i + 3];
      dst[i] = ov;
    }
  }
}

// ---------------------------------------------------------------------------
extern "C" void kernel_launch(void* const* d_in, const int* in_sizes, int n_in,
                              void* d_out, int out_size, void* d_ws, size_t ws_size,
                              hipStream_t stream) {
  (void)in_sizes; (void)n_in; (void)out_size; (void)ws_size;

  float* out = (float*)d_out;
  float* out_edges = out;                       // [1024,256]
  float* out_H = out + NSL * DD;                // [65536,1024]
  float* out_d2 = out_H + NN * NSL;             // [65536,1024]

  // H region scratch (every occupant dead before d3h overwrites with H):
  char* Hb = (char*)out_H;
  u16* dots = (u16*)Hb;                          // 134217728 B
  u16* xln = (u16*)(Hb + 134217728L);            // 32 MB
  u16* kb_ = (u16*)(Hb + 167772160L);            // 32 MB
  u16* vb_ = (u16*)(Hb + 201326592L);            // 32 MB
  char* smb = Hb + 234881024L;
  u16* wcat = (u16*)smb;      smb += 768 * 256 * 2;
  float* bcat = (float*)smb;  smb += 4096;
  float* e_f = (float*)smb;   smb += 1024 * 256 * 4;
  u16* e_b = (u16*)smb;       smb += 1024 * 256 * 2;
  u16* q_b = (u16*)smb;       smb += 1024 * 256 * 2;
  float* updf = (float*)smb;  smb += 1024 * 256 * 4;
  u16* edg_b = (u16*)smb;     smb += 1024 * 256 * 2;
  // dots2 region holds the strided q2 tiles (consumed block-locally by d3h).
  u16* q2s = (u16*)out_d2;
  // k2 in workspace (512 KB): the only scratch that must survive into d3h.
  u16* k2ws = (u16*)d_ws;

  hipFuncSetAttribute(reinterpret_cast<const void*>(d3h_kernel),
                      hipFuncAttributeMaxDynamicSharedMemorySize,
                      (int)sizeof(D3HShm));

  prep_w_kernel<<<768, 256, 0, stream>>>(
      (const float*)d_in[4], (const float*)d_in[6], (const float*)d_in[8],
      (const float*)d_in[5], (const float*)d_in[7], (const float*)d_in[9], wcat, bcat);
  edges_e_kernel<<<256, 256, 0, stream>>>(
      (const float*)d_in[1], (const float*)d_in[2], (const float*)d_in[3],
      (const float*)d_in[16], (const float*)d_in[17], e_f, e_b);
  ln_x_kernel<<<16384, 256, 0, stream>>>(
      (const float*)d_in[0], (const float*)d_in[14], (const float*)d_in[15], xln);
  gemm_bt<1><<<dim3(2, 8), 256, 0, stream>>>(e_b, wcat + 512 * 256, bcat + 512, 1.f,
                                             q_b, nullptr, nullptr, nullptr);
  gemm_bt<0><<<dim3(6, 512), 256, 0, stream>>>(xln, wcat, bcat, 1.f,
                                               kb_, vb_, q2s, nullptr);
  gemm_bt<2><<<dim3(512, 8), 256, 0, stream>>>(q_b, kb_, nullptr, 0.0625f,
                                               dots, nullptr, nullptr, nullptr);
  d2d3_kernel<<<1024, 256, 0, stream>>>(dots, vb_, (const int*)d_in[18], updf);
  mlp_kernel<<<1024, 256, 0, stream>>>(e_f, updf,
                                       (const float*)d_in[10], (const float*)d_in[11],
                                       (const float*)d_in[12], (const float*)d_in[13],
                                       out_edges, edg_b);
  gemm_bt<1><<<dim3(2, 8), 256, 0, stream>>>(edg_b, wcat, bcat, 1.f,
                                             k2ws, nullptr, nullptr, nullptr);
  d3h_kernel<<<2048, 512, sizeof(D3HShm), stream>>>(q2s, k2ws, (const int*)d_in[19],
                                                    out_d2, out_H);
}

// Round 12
// 645.055 us; speedup vs baseline: 1.1602x; 1.1602x over previous
//
#include <hip/hip_runtime.h>
#include <hip/hip_bf16.h>
#include <stdint.h>

// ---------------------------------------------------------------------------
// HConstructor: slot-attention-like block on MI355X.
//   inputs [65536,256], noise [1024,256] -> edges [1024,256], H [65536,1024],
//   dots2 [65536,1024].
// Pipeline (all on `stream`):
//   prep_w   : Wcat^T = [wk|wv|wq]^T as bf16 [768,256], bias cat
//   edges_e  : edges = mu + exp(ls)*noise ; e = LN(edges)  (f32 + bf16)
//   ln_x     : x = LN(inputs) -> bf16 [65536,256]
//   gemm<1>  : q  = relu(e @ wq + bq)           [1024,256]  bf16
//   gemm<0>  : k,v = relu(x@wk/v + b) -> H-region; q2 strided into dots2 rows
//   gemm<2>  : dots = (q @ k^T) * 1/16 -> bf16 [1024,65536] (H-region scratch)
//   d2d3 v2  : 3-pass streaming rank-select, ~27 KB LDS, all 1024 blocks
//              co-resident.  MEASURED ~53 us (R11 attribution).
//   mlp      : edges_out = relu([e,upd]@w1+b1)@w2+b2 -> OUT + bf16
//   gemm<1>  : k2 = relu(edges_out @ wk + bk) -> d_ws (512 KB)
//   d3h v3   : FUSED dots2 + H (REVERTED to R9's measured-199us structure).
//              Variant ledger: v3=199 / v4 dbuf=~308 / v5 no-barrier=404 /
//              R8 LDS-tile=623 / R7 round-trip=410.  v4/v5 lost to compiler
//              rematerialization (VGPR=32 proves afrag wasn't register-held)
//              and latency-exposed schedules; v3's LDS-staged Aq + single-
//              buffered Bk with compiler waitcnts wins.  Do not "improve"
//              without within-run A/B evidence.
// Scratch map:
//   H region   : dots(134M) | xln(32M) | kb(32M) | vb(32M) | smalls(~4M)
//   dots2 reg. : q2-strided tiles (consumed block-locally by d3h)
//   d_ws       : k2 bf16 (512 KB)
// ---------------------------------------------------------------------------

#define DEV __device__ __forceinline__

typedef uint32_t u32;
typedef uint16_t u16;
typedef __bf16 v8bf __attribute__((ext_vector_type(8)));
typedef float v4f __attribute__((ext_vector_type(4)));

static constexpr long NN = 65536;
static constexpr long DD = 256;
static constexpr long NSL = 1024;

DEV u16 f2b(float f) {
  u32 u = __builtin_bit_cast(u32, f);
  u32 r = (u + 0x7FFFu + ((u >> 16) & 1u)) >> 16;
  return (u16)r;
}
DEV float b2f(u16 h) { u32 u = ((u32)h) << 16; return __builtin_bit_cast(float, u); }
// bf16 bits (as u32 low16) -> monotone sortable 16-bit key
DEV u32 b2k(u32 b) { return b ^ (0x8000u + 0x7FFFu * (b >> 15)); }
DEV float k2fv(u32 k) {
  u16 b = (k & 0x8000u) ? (u16)(k ^ 0x8000u) : (u16)(k ^ 0xFFFFu);
  return b2f(b);
}

// ---------------------------------------------------------------------------
// Generic  C[M,N] = epilogue(A[M,256] @ B[N,256]^T)   (bf16 in, MFMA 16x16x32)
// 128x128 tile, BK=64, 4 waves (2x2), XOR-swizzled LDS (16B chunk ^ row&7).
// EPI 0: +biascat, relu for cols<512, route {0:k,1:v,2:q2-strided} bf16
// EPI 1: +bias, relu, bf16 out [M,256]
// EPI 2: *scale, bf16 out ld=65536
// ---------------------------------------------------------------------------
template <int EPI>
__global__ __launch_bounds__(256, 2)
void gemm_bt(const u16* __restrict__ A, const u16* __restrict__ B,
             const float* __restrict__ bias, float scale,
             u16* __restrict__ ob0, u16* __restrict__ ob1, u16* __restrict__ ob2,
             float* __restrict__ of) {
  __shared__ __align__(16) u16 As[128 * 64];
  __shared__ __align__(16) u16 Bs[128 * 64];
  const int tid = threadIdx.x;
  const int lane = tid & 63;
  const int l15 = lane & 15;
  const int l4 = lane >> 4;
  const int wid = tid >> 6;
  const int wm = wid >> 1, wn = wid & 1;
  const long m0 = (long)blockIdx.y * 128;
  const long n0 = (long)blockIdx.x * 128;

  v4f acc[4][4] = {};

  for (int kb = 0; kb < 256; kb += 64) {
    __syncthreads();
#pragma unroll
    for (int i = 0; i < 4; i++) {
      int cid = tid + 256 * i;          // 1024 16B-chunks per tile
      int row = cid >> 3, ch = cid & 7; // 8 chunks per 64-col row
      int sch = ch ^ (row & 7);
      uint4 da = *reinterpret_cast<const uint4*>(A + (m0 + row) * 256 + kb + ch * 8);
      *reinterpret_cast<uint4*>(&As[row * 64 + sch * 8]) = da;
      uint4 db = *reinterpret_cast<const uint4*>(B + (n0 + row) * 256 + kb + ch * 8);
      *reinterpret_cast<uint4*>(&Bs[row * 64 + sch * 8]) = db;
    }
    __syncthreads();
#pragma unroll
    for (int ks = 0; ks < 2; ks++) {
      v8bf af[4], bfr[4];
#pragma unroll
      for (int m = 0; m < 4; m++) {
        int row = wm * 64 + m * 16 + l15;
        int sch = (ks * 4 + l4) ^ (row & 7);
        af[m] = *reinterpret_cast<const v8bf*>(&As[row * 64 + sch * 8]);
      }
#pragma unroll
      for (int n = 0; n < 4; n++) {
        int row = wn * 64 + n * 16 + l15;
        int sch = (ks * 4 + l4) ^ (row & 7);
        bfr[n] = *reinterpret_cast<const v8bf*>(&Bs[row * 64 + sch * 8]);
      }
#pragma unroll
      for (int m = 0; m < 4; m++)
#pragma unroll
        for (int n = 0; n < 4; n++)
          acc[m][n] = __builtin_amdgcn_mfma_f32_16x16x32_bf16(af[m], bfr[n], acc[m][n], 0, 0, 0);
    }
  }

  const int r4 = l4 * 4;
#pragma unroll
  for (int m = 0; m < 4; m++) {
#pragma unroll
    for (int n = 0; n < 4; n++) {
#pragma unroll
      for (int r = 0; r < 4; r++) {
        long grow = m0 + wm * 64 + m * 16 + r4 + r;
        long gcol = n0 + wn * 64 + n * 16 + l15;
        float v = acc[m][n][r];
        if constexpr (EPI == 0) {
          v += bias[gcol];
          int which = (int)(gcol >> 8);
          long jj = gcol & 255;
          if (which < 2) v = fmaxf(v, 0.f);
          u16 hv = f2b(v);
          if (which == 0) ob0[grow * 256 + jj] = hv;
          else if (which == 1) ob1[grow * 256 + jj] = hv;
          else ob2[(grow & ~31L) * 2048 + (grow & 31) * 256 + jj] = hv;  // q2 strided
        } else if constexpr (EPI == 1) {
          v += bias[gcol];
          v = fmaxf(v, 0.f);
          ob0[grow * 256 + gcol] = f2b(v);
        } else if constexpr (EPI == 2) {
          ob0[grow * 65536 + gcol] = f2b(v * scale);
        } else {
          of[grow * 1024 + gcol] = v * scale;
        }
      }
    }
  }
}

// ---------------------------------------------------------------------------
// Weight prep: Wcat^T bf16 [768,256] rows = [wk cols | wv cols | wq cols]
// ---------------------------------------------------------------------------
__global__ __launch_bounds__(256)
void prep_w_kernel(const float* __restrict__ wq, const float* __restrict__ wk,
                   const float* __restrict__ wv, const float* __restrict__ bq,
                   const float* __restrict__ bk, const float* __restrict__ bv,
                   u16* __restrict__ wcat, float* __restrict__ bcat) {
  int n = blockIdx.x;
  int t = threadIdx.x;
  const float* W = (n < 256) ? wk : (n < 512) ? wv : wq;
  int jj = n & 255;
  wcat[n * 256 + t] = f2b(W[t * 256 + jj]);
  if (t == 0) {
    const float* Bb = (n < 256) ? bk : (n < 512) ? bv : bq;
    bcat[n] = Bb[jj];
  }
}

// ---------------------------------------------------------------------------
// x = LayerNorm(inputs) -> bf16.  One wave per row (4 f32 per lane).
// ---------------------------------------------------------------------------
__global__ __launch_bounds__(256)
void ln_x_kernel(const float* __restrict__ x, const float* __restrict__ lw,
                 const float* __restrict__ lb, u16* __restrict__ out) {
  const int lane = threadIdx.x & 63, wid = threadIdx.x >> 6;
  const long row = (long)blockIdx.x * 4 + wid;
  float4 v = reinterpret_cast<const float4*>(x + row * 256)[lane];
  float s = v.x + v.y + v.z + v.w;
  for (int sh = 1; sh < 64; sh <<= 1) s += __shfl_xor(s, sh);
  float mu = s * (1.f / 256.f);
  float dx = v.x - mu, dy = v.y - mu, dz = v.z - mu, dw = v.w - mu;
  float q = dx * dx + dy * dy + dz * dz + dw * dw;
  for (int sh = 1; sh < 64; sh <<= 1) q += __shfl_xor(q, sh);
  float rs = rsqrtf(q * (1.f / 256.f) + 1e-5f);
  float4 wv = reinterpret_cast<const float4*>(lw)[lane];
  float4 bv = reinterpret_cast<const float4*>(lb)[lane];
  ushort4 o4;
  o4.x = f2b(dx * rs * wv.x + bv.x);
  o4.y = f2b(dy * rs * wv.y + bv.y);
  o4.z = f2b(dz * rs * wv.z + bv.z);
  o4.w = f2b(dw * rs * wv.w + bv.w);
  reinterpret_cast<ushort4*>(out + row * 256)[lane] = o4;
}

// ---------------------------------------------------------------------------
// edges = mu + exp(ls)*noise ; e = LayerNorm(edges) -> f32 + bf16
// ---------------------------------------------------------------------------
__global__ __launch_bounds__(256)
void edges_e_kernel(const float* __restrict__ noise, const float* __restrict__ emu,
                    const float* __restrict__ els, const float* __restrict__ lw,
                    const float* __restrict__ lb, float* __restrict__ e_f,
                    u16* __restrict__ e_b) {
  const int lane = threadIdx.x & 63, wid = threadIdx.x >> 6;
  const long row = (long)blockIdx.x * 4 + wid;
  float4 nz = reinterpret_cast<const float4*>(noise + row * 256)[lane];
  float4 mu4 = reinterpret_cast<const float4*>(emu)[lane];
  float4 ls4 = reinterpret_cast<const float4*>(els)[lane];
  float4 ed;
  ed.x = mu4.x + expf(ls4.x) * nz.x;
  ed.y = mu4.y + expf(ls4.y) * nz.y;
  ed.z = mu4.z + expf(ls4.z) * nz.z;
  ed.w = mu4.w + expf(ls4.w) * nz.w;
  float s = ed.x + ed.y + ed.z + ed.w;
  for (int sh = 1; sh < 64; sh <<= 1) s += __shfl_xor(s, sh);
  float mu = s * (1.f / 256.f);
  float dx = ed.x - mu, dy = ed.y - mu, dz = ed.z - mu, dw = ed.w - mu;
  float qv = dx * dx + dy * dy + dz * dz + dw * dw;
  for (int sh = 1; sh < 64; sh <<= 1) qv += __shfl_xor(qv, sh);
  float rs = rsqrtf(qv * (1.f / 256.f) + 1e-5f);
  float4 wv = reinterpret_cast<const float4*>(lw)[lane];
  float4 bv = reinterpret_cast<const float4*>(lb)[lane];
  float4 ef;
  ef.x = dx * rs * wv.x + bv.x;
  ef.y = dy * rs * wv.y + bv.y;
  ef.z = dz * rs * wv.z + bv.z;
  ef.w = dw * rs * wv.w + bv.w;
  reinterpret_cast<float4*>(e_f + row * 256)[lane] = ef;
  ushort4 o4;
  o4.x = f2b(ef.x); o4.y = f2b(ef.y); o4.z = f2b(ef.z); o4.w = f2b(ef.w);
  reinterpret_cast<ushort4*>(e_b + row * 256)[lane] = o4;
}

// ---------------------------------------------------------------------------
// d2d3 v2 (unchanged; measured ~53us): one block (256 threads) per q-row,
// ~27 KB LDS, all 1024 blocks co-resident.  3-pass streaming histogram
// rank-select + sparse attn@v gather.  Fixed softmax shift C=8.
// ---------------------------------------------------------------------------
struct D2Shm {
  u32 hist[256 * 16];     // 16 KiB: bin b, copy c at [b*16+c]
  u32 c_hi[256];
  u32 sel_idx[1152];
  float sel_w[1152];
  float fred[4];
  u32 sb_star, sThi, sThr;
  float sSE, sFrac;
  u32 scnt;
};

__global__ __launch_bounds__(256, 5)
void d2d3_kernel(const u16* __restrict__ dots, const u16* __restrict__ vmat,
                 const int* __restrict__ knp, float* __restrict__ upd) {
  __shared__ D2Shm S;
  const int tid = threadIdx.x, lane = tid & 63, wid = tid >> 6;
  const int hc = (lane >> 2);          // 16 lane-indexed histogram copies
  const long r = blockIdx.x;
  const int kn = *knp;

  for (int i = tid; i < 4096; i += 256) S.hist[i] = 0;
  if (tid == 0) S.scnt = 0;
  __syncthreads();

  const float C = 8.f;  // fixed softmax shift (dots >= 0 since q,k relu'd)
  const uint4* src = reinterpret_cast<const uint4*>(dots + r * 65536);

  // ---- pass 1: high-byte histogram + sum-exp ----
  float se = 0.f;
  for (int c = tid; c < 8192; c += 256) {
    uint4 d = src[c];
    u32 h[8] = {d.x & 0xffffu, d.x >> 16, d.y & 0xffffu, d.y >> 16,
                d.z & 0xffffu, d.z >> 16, d.w & 0xffffu, d.w >> 16};
#pragma unroll
    for (int j = 0; j < 8; j++) {
      u32 k = b2k(h[j]);
      se += __expf(b2f((u16)h[j]) - C);
      atomicAdd(&S.hist[(k >> 8) * 16 + hc], 1u);
    }
  }
  for (int sh = 1; sh < 64; sh <<= 1) se += __shfl_xor(se, sh);
  if (lane == 0) S.fred[wid] = se;
  __syncthreads();

  // reduce copies -> c_hi
  {
    u32 s = 0;
#pragma unroll
    for (int c = 0; c < 16; c++) s += S.hist[tid * 16 + c];
    S.c_hi[tid] = s;
  }
  __syncthreads();

  // ---- scan 1: wave 0 -> b*, Thi;  waves 1-3 re-zero hist ----
  if (tid < 64) {
    u32 s = S.c_hi[4 * tid] + S.c_hi[4 * tid + 1] + S.c_hi[4 * tid + 2] + S.c_hi[4 * tid + 3];
    u32 v = s;
    for (int off = 1; off < 64; off <<= 1) {
      u32 t = (u32)__shfl_down((int)v, off);
      if (tid + off < 64) v += t;        // inclusive suffix sum over lanes
    }
    u32 excl = v - s;
    if (v >= (u32)kn && excl < (u32)kn) {
      u32 acc = excl;
#pragma unroll
      for (int bb = 3; bb >= 0; --bb) {
        int b = 4 * tid + bb;
        u32 nb = acc + S.c_hi[b];
        if (nb >= (u32)kn) { S.sb_star = (u32)b; S.sThi = acc; break; }
        acc = nb;
      }
    }
  } else {
    for (int i = tid - 64; i < 4096; i += 192) S.hist[i] = 0;
  }
  __syncthreads();
  const u32 bstar = S.sb_star;

  // ---- pass 2: low-byte histogram within bin b* (row re-read, L3-hot) ----
  for (int c = tid; c < 8192; c += 256) {
    uint4 d = src[c];
    u32 h[8] = {d.x & 0xffffu, d.x >> 16, d.y & 0xffffu, d.y >> 16,
                d.z & 0xffffu, d.z >> 16, d.w & 0xffffu, d.w >> 16};
#pragma unroll
    for (int j = 0; j < 8; j++) {
      u32 k = b2k(h[j]);
      if ((k >> 8) == bstar) atomicAdd(&S.hist[(k & 255u) * 16 + hc], 1u);
    }
  }
  __syncthreads();
  {
    u32 s = 0;
#pragma unroll
    for (int c = 0; c < 16; c++) s += S.hist[tid * 16 + c];
    S.c_hi[tid] = s;
  }
  __syncthreads();

  // ---- scan 2: wave 0 -> exact threshold, tie counts, SE ----
  if (tid < 64) {
    u32 s = S.c_hi[4 * tid] + S.c_hi[4 * tid + 1] + S.c_hi[4 * tid + 2] + S.c_hi[4 * tid + 3];
    u32 v = s;
    for (int off = 1; off < 64; off <<= 1) {
      u32 t = (u32)__shfl_down((int)v, off);
      if (tid + off < 64) v += t;
    }
    const u32 Thi = S.sThi;              // count(high byte > b*)
    u32 incl = v + Thi;
    u32 excl = v - s + Thi;
    if (incl >= (u32)kn && excl < (u32)kn) {
      u32 acc = excl;
#pragma unroll
      for (int bb = 3; bb >= 0; --bb) {
        int b = 4 * tid + bb;
        u32 nb = acc + S.c_hi[b];
        if (nb >= (u32)kn) {
          S.sThr = (bstar << 8) | (u32)b;
          // acc = count(key > thr), c_hi[b] = count(key == thr)
          S.sFrac = (float)(int)((u32)kn - acc) / (float)S.c_hi[b];
          break;
        }
        acc = nb;
      }
    }
    if (tid == 0) {
      float SE = S.fred[0] + S.fred[1] + S.fred[2] + S.fred[3];
      S.sSE = SE;
    }
  }
  __syncthreads();
  const u32 thr = S.sThr;
  const float frac = S.sFrac;
  const float invs = 1.f / S.sSE;
  const float wnorm = 1.f / (1.f + 65536.f * 1e-8f);

  // ---- pass 3: selection: keys >= thr -> (global idx, weight) list ----
  for (int c = tid; c < 8192; c += 256) {
    uint4 d = src[c];
    u32 h[8] = {d.x & 0xffffu, d.x >> 16, d.y & 0xffffu, d.y >> 16,
                d.z & 0xffffu, d.z >> 16, d.w & 0xffffu, d.w >> 16};
#pragma unroll
    for (int j = 0; j < 8; j++) {
      u32 k = b2k(h[j]);
      if (k >= thr) {
        float w = (__expf(k2fv(k) - C) * invs + 1e-8f) * wnorm;
        if (k == thr) w *= frac;
        u32 p = atomicAdd(&S.scnt, 1u);
        if (p < 1152u) { S.sel_idx[p] = (u32)c * 8u + (u32)j; S.sel_w[p] = w; }
      }
    }
  }
  __syncthreads();
  const u32 nsel = S.scnt < 1152u ? S.scnt : 1152u;

  // ---- gather: thread t owns output col t; 4-deep ILP ----
  float a0 = 0.f, a1 = 0.f, a2 = 0.f, a3 = 0.f;
  u32 j = 0;
  for (; j + 3 < nsel; j += 4) {
    a0 = fmaf(S.sel_w[j], b2f(vmat[(long)S.sel_idx[j] * 256 + tid]), a0);
    a1 = fmaf(S.sel_w[j + 1], b2f(vmat[(long)S.sel_idx[j + 1] * 256 + tid]), a1);
    a2 = fmaf(S.sel_w[j + 2], b2f(vmat[(long)S.sel_idx[j + 2] * 256 + tid]), a2);
    a3 = fmaf(S.sel_w[j + 3], b2f(vmat[(long)S.sel_idx[j + 3] * 256 + tid]), a3);
  }
  for (; j < nsel; ++j)
    a0 = fmaf(S.sel_w[j], b2f(vmat[(long)S.sel_idx[j] * 256 + tid]), a0);
  upd[r * 256 + tid] = (a0 + a1) + (a2 + a3);
}

// ---------------------------------------------------------------------------
// mlp: edges_out = relu([e, upd] @ w1 + b1) @ w2 + b2   (f32, one block/row)
// ---------------------------------------------------------------------------
__global__ __launch_bounds__(256)
void mlp_kernel(const float* __restrict__ e, const float* __restrict__ upd,
                const float* __restrict__ w1, const float* __restrict__ b1,
                const float* __restrict__ w2, const float* __restrict__ b2,
                float* __restrict__ eout, u16* __restrict__ eb) {
  __shared__ float ecat[512];
  __shared__ float h[256];
  const int t = threadIdx.x;
  const long r = blockIdx.x;
  ecat[t] = e[r * 256 + t];
  ecat[256 + t] = upd[r * 256 + t];
  __syncthreads();
  float acc = b1[t];
#pragma unroll 8
  for (int kk = 0; kk < 512; ++kk) acc = fmaf(ecat[kk], w1[kk * 256 + t], acc);
  h[t] = fmaxf(acc, 0.f);
  __syncthreads();
  float a2 = b2[t];
#pragma unroll 8
  for (int kk = 0; kk < 256; ++kk) a2 = fmaf(h[kk], w2[kk * 256 + t], a2);
  eout[r * 256 + t] = a2;
  eb[r * 256 + t] = f2b(a2);
}

// ---------------------------------------------------------------------------
// d3h v3 (REVERT to R9's measured-199us kernel, byte-for-byte):
// FUSED dots2 + H at 2 blocks/CU.  One block = 32 rows, 512 threads,
// 8 waves as 2M(16 rows) x 4N(16 cols each within a 64-col chunk).
//   phase 1: stage q2 tile [32][256] swizzled (16 KB LDS)
//   phase 2: 16 col-chunks x 4 kb: stage Bk[64][64] (8 KB), MFMA;
//            acc -> stg (f32, 8 KB) + keys (bf16); coalesced 256 B-segment
//            float4 writes of dots2 per stripe.
//   phase 3: per-wave top-ke over 4 rows from bf16 keys; H written 64 B/lane.
// LDS = keys 64K + Aq 16K + ... NOTE: R9 layout = keys 64K + stg 8K + Bk 8K
// = 80 KB with A fragments in LDS-staged Aq?  R9 v3 used REGISTER afrag
// loaded once pre-loop (VGPR ~64); keep exactly that.
// ---------------------------------------------------------------------------
struct D3HShm {
  u16 keys[32 * 1024];     // 64 KiB bf16 dots2 values
  float stg[32 * 64];      // 8 KiB f32 write-staging (one 64-col stripe)
  u16 Bk[64 * 64];         // 8 KiB
};

__global__ __launch_bounds__(512, 4)
void d3h_kernel(const u16* __restrict__ q2s, const u16* __restrict__ k2,
                const int* __restrict__ kep, float* __restrict__ d2out,
                float* __restrict__ H) {
  extern __shared__ char d3hsm[];
  D3HShm* S = reinterpret_cast<D3HShm*>(d3hsm);
  const int tid = threadIdx.x;
  const int lane = tid & 63;
  const int l15 = lane & 15;
  const int l4 = lane >> 4;
  const int w = tid >> 6;
  const int wm = w >> 2, wn = w & 3;
  const long m0 = (long)blockIdx.x * 32;

  // ---- A fragments into registers (one-time; q2 tile is 16 KB, L2-hot) ----
  const u16* q2blk = q2s + m0 * 2048;          // own strided slot
  const int arow = wm * 16 + l15;
  v8bf afrag[8];
#pragma unroll
  for (int kb = 0; kb < 4; kb++)
#pragma unroll
    for (int ks = 0; ks < 2; ks++)
      afrag[kb * 2 + ks] = *reinterpret_cast<const v8bf*>(
          q2blk + arow * 256 + kb * 64 + ks * 32 + l4 * 8);

  const int brow = wn * 16 + l15;

  // ---- 16 col-chunks of 64 ----
#pragma unroll 1
  for (int nc = 0; nc < 16; nc++) {
    v4f acc = {};
#pragma unroll
    for (int kb = 0; kb < 4; kb++) {
      __syncthreads();                         // also guards stg reuse
      {
        int row = tid >> 3, ch = tid & 7;      // 512 x 16B chunks
        int sch = ch ^ (row & 7);
        uint4 d = *reinterpret_cast<const uint4*>(k2 + (nc * 64 + row) * 256 + kb * 64 + ch * 8);
        *reinterpret_cast<uint4*>(&S->Bk[row * 64 + sch * 8]) = d;
      }
      __syncthreads();
#pragma unroll
      for (int ks = 0; ks < 2; ks++) {
        v8bf b = *reinterpret_cast<const v8bf*>(
            &S->Bk[brow * 64 + (((ks * 4 + l4) ^ (brow & 7))) * 8]);
        acc = __builtin_amdgcn_mfma_f32_16x16x32_bf16(afrag[kb * 2 + ks], b, acc, 0, 0, 0);
      }
    }
    // scale; stash f32 into stg and bf16 into keys
#pragma unroll
    for (int r = 0; r < 4; r++) {
      int lr = wm * 16 + l4 * 4 + r;           // 0..31
      int lc = wn * 16 + l15;                  // 0..63
      float v = acc[r] * 0.0625f;
      S->stg[lr * 64 + lc] = v;
      S->keys[lr * 1024 + nc * 64 + lc] = f2b(v);
    }
    __syncthreads();
    // coalesced dots2 write of this 64-col stripe (256 B segments)
    {
      int row = tid >> 4;                      // 0..31
      int c4 = (tid & 15) * 4;                 // 0..60
      float4 v = *reinterpret_cast<const float4*>(&S->stg[row * 64 + c4]);
      *reinterpret_cast<float4*>(&d2out[(m0 + row) * 1024 + nc * 64 + c4]) = v;
    }
  }
  __syncthreads();

  // ---- top-ke phase: wave w owns rows m0 + w*4 .. +3, from bf16 keys ----
  const int ke = *kep;
#pragma unroll
  for (int j = 0; j < 4; j++) {
    const int lrow = w * 4 + j;
    const long row = m0 + lrow;
    uint4 ka = *reinterpret_cast<const uint4*>(&S->keys[lrow * 1024 + lane * 16]);
    uint4 kb2 = *reinterpret_cast<const uint4*>(&S->keys[lrow * 1024 + lane * 16 + 8]);
    u32 kw[8] = {ka.x, ka.y, ka.z, ka.w, kb2.x, kb2.y, kb2.z, kb2.w};
    u32 k16[16];
    float x[16];
#pragma unroll
    for (int i = 0; i < 8; i++) {
      u32 lo16 = kw[i] & 0xffffu, hi16 = kw[i] >> 16;
      k16[2 * i] = b2k(lo16);     x[2 * i] = b2f((u16)lo16);
      k16[2 * i + 1] = b2k(hi16); x[2 * i + 1] = b2f((u16)hi16);
    }
    float mx = x[0];
#pragma unroll
    for (int i = 1; i < 16; i++) mx = fmaxf(mx, x[i]);
    for (int sh = 1; sh < 64; sh <<= 1) mx = fmaxf(mx, __shfl_xor(mx, sh));
    float p[16];
    float se = 0.f;
#pragma unroll
    for (int i = 0; i < 16; i++) { p[i] = __expf(x[i] - mx); se += p[i]; }
    for (int sh = 1; sh < 64; sh <<= 1) se += __shfl_xor(se, sh);
    const float invs = 1.f / se;
    u32 lo = 0;
    for (int b = 15; b >= 0; --b) {
      u32 t = lo | (1u << b);
      int cnt = 0;
#pragma unroll
      for (int i = 0; i < 16; i++) cnt += (k16[i] >= t);
      for (int sh = 1; sh < 64; sh <<= 1) cnt += __shfl_xor(cnt, sh);
      if (cnt >= ke) lo = t;
    }
    float o[16];
#pragma unroll
    for (int i = 0; i < 16; i++) o[i] = (k16[i] >= lo) ? p[i] * invs : 0.f;
    float4* dst = reinterpret_cast<float4*>(&H[row * 1024 + lane * 16]);
#pragma unroll
    for (int i = 0; i < 4; i++) {
      float4 ov;
      ov.x = o[4 * i]; ov.y = o[4 * i + 1]; ov.z = o[4 * i + 2]; ov.w = o[4 * i + 3];
      dst[i] = ov;
    }
  }
}

// ---------------------------------------------------------------------------
extern "C" void kernel_launch(void* const* d_in, const int* in_sizes, int n_in,
                              void* d_out, int out_size, void* d_ws, size_t ws_size,
                              hipStream_t stream) {
  (void)in_sizes; (void)n_in; (void)out_size; (void)ws_size;

  float* out = (float*)d_out;
  float* out_edges = out;                       // [1024,256]
  float* out_H = out + NSL * DD;                // [65536,1024]
  float* out_d2 = out_H + NN * NSL;             // [65536,1024]

  // H region scratch (every occupant dead before d3h overwrites with H):
  char* Hb = (char*)out_H;
  u16* dots = (u16*)Hb;                          // 134217728 B
  u16* xln = (u16*)(Hb + 134217728L);            // 32 MB
  u16* kb_ = (u16*)(Hb + 167772160L);            // 32 MB
  u16* vb_ = (u16*)(Hb + 201326592L);            // 32 MB
  char* smb = Hb + 234881024L;
  u16* wcat = (u16*)smb;      smb += 768 * 256 * 2;
  float* bcat = (float*)smb;  smb += 4096;
  float* e_f = (float*)smb;   smb += 1024 * 256 * 4;
  u16* e_b = (u16*)smb;       smb += 1024 * 256 * 2;
  u16* q_b = (u16*)smb;       smb += 1024 * 256 * 2;
  float* updf = (float*)smb;  smb += 1024 * 256 * 4;
  u16* edg_b = (u16*)smb;     smb += 1024 * 256 * 2;
  // dots2 region holds the strided q2 tiles (consumed block-locally by d3h).
  u16* q2s = (u16*)out_d2;
  // k2 in workspace (512 KB): the only scratch that must survive into d3h.
  u16* k2ws = (u16*)d_ws;

  hipFuncSetAttribute(reinterpret_cast<const void*>(d3h_kernel),
                      hipFuncAttributeMaxDynamicSharedMemorySize,
                      (int)sizeof(D3HShm));

  prep_w_kernel<<<768, 256, 0, stream>>>(
      (const float*)d_in[4], (const float*)d_in[6], (const float*)d_in[8],
      (const float*)d_in[5], (const float*)d_in[7], (const float*)d_in[9], wcat, bcat);
  edges_e_kernel<<<256, 256, 0, stream>>>(
      (const float*)d_in[1], (const float*)d_in[2], (const float*)d_in[3],
      (const float*)d_in[16], (const float*)d_in[17], e_f, e_b);
  ln_x_kernel<<<16384, 256, 0, stream>>>(
      (const float*)d_in[0], (const float*)d_in[14], (const float*)d_in[15], xln);
  gemm_bt<1><<<dim3(2, 8), 256, 0, stream>>>(e_b, wcat + 512 * 256, bcat + 512, 1.f,
                                             q_b, nullptr, nullptr, nullptr);
  gemm_bt<0><<<dim3(6, 512), 256, 0, stream>>>(xln, wcat, bcat, 1.f,
                                               kb_, vb_, q2s, nullptr);
  gemm_bt<2><<<dim3(512, 8), 256, 0, stream>>>(q_b, kb_, nullptr, 0.0625f,
                                               dots, nullptr, nullptr, nullptr);
  d2d3_kernel<<<1024, 256, 0, stream>>>(dots, vb_, (const int*)d_in[18], updf);
  mlp_kernel<<<1024, 256, 0, stream>>>(e_f, updf,
                                       (const float*)d_in[10], (const float*)d_in[11],
                                       (const float*)d_in[12], (const float*)d_in[13],
                                       out_edges, edg_b);
  gemm_bt<1><<<dim3(2, 8), 256, 0, stream>>>(edg_b, wcat, bcat, 1.f,
                                             k2ws, nullptr, nullptr, nullptr);
  d3h_kernel<<<2048, 512, sizeof(D3HShm), stream>>>(q2s, k2ws, (const int*)d_in[19],
                                                    out_d2, out_H);
}

// Round 13
// 644.628 us; speedup vs baseline: 1.1610x; 1.0007x over previous
//
#include <hip/hip_runtime.h>
#include <hip/hip_bf16.h>
#include <stdint.h>

// ---------------------------------------------------------------------------
// HConstructor: slot-attention-like block on MI355X.
//   inputs [65536,256], noise [1024,256] -> edges [1024,256], H [65536,1024],
//   dots2 [65536,1024].
// Pipeline (all on `stream`):
//   prep_w   : Wcat^T = [wk|wv|wq]^T as bf16 [768,256], bias cat
//   edges_e  : edges = mu + exp(ls)*noise ; e = LN(edges)  (f32 + bf16)
//   ln_x     : x = LN(inputs) -> bf16 [65536,256]
//   gemm<1>  : q  = relu(e @ wq + bq)           [1024,256]  bf16
//   gemm<0>  : k,v = relu(x@wk/v + b) -> H-region; q2 strided into dots2 rows
//   gemm<2>  : dots = (q @ k^T) * 1/16 -> bf16 [1024,65536] (H-region scratch)
//   d2d3 v2  : 3-pass streaming rank-select, ~27 KB LDS, all blocks
//              co-resident.
//   mlp      : edges_out = relu([e,upd]@w1+b1)@w2+b2 -> OUT + bf16
//   gemm<1>  : k2 = relu(edges_out @ wk + bk) -> d_ws (512 KB)
//   d3h v6   : = v3 + ASM-PINNED afrag.  Corrected ledger (R11/R12 hard
//              A/B): v3=301, v4=308 (VGPR=36 -> afrag rematerialized into
//              the loop, L2 reload per kb-step), v5=404, split=297.  v6
//              pins afrag with asm volatile("" : "+v") so the 8 v8bf A
//              fragments STAY in registers; otherwise byte-identical to v3.
// Scratch map:
//   H region   : dots(134M) | xln(32M) | kb(32M) | vb(32M) | smalls(~4M)
//   dots2 reg. : q2-strided tiles (consumed block-locally by d3h)
//   d_ws       : k2 bf16 (512 KB)
// ---------------------------------------------------------------------------

#define DEV __device__ __forceinline__

typedef uint32_t u32;
typedef uint16_t u16;
typedef __bf16 v8bf __attribute__((ext_vector_type(8)));
typedef float v4f __attribute__((ext_vector_type(4)));

static constexpr long NN = 65536;
static constexpr long DD = 256;
static constexpr long NSL = 1024;

DEV u16 f2b(float f) {
  u32 u = __builtin_bit_cast(u32, f);
  u32 r = (u + 0x7FFFu + ((u >> 16) & 1u)) >> 16;
  return (u16)r;
}
DEV float b2f(u16 h) { u32 u = ((u32)h) << 16; return __builtin_bit_cast(float, u); }
// bf16 bits (as u32 low16) -> monotone sortable 16-bit key
DEV u32 b2k(u32 b) { return b ^ (0x8000u + 0x7FFFu * (b >> 15)); }
DEV float k2fv(u32 k) {
  u16 b = (k & 0x8000u) ? (u16)(k ^ 0x8000u) : (u16)(k ^ 0xFFFFu);
  return b2f(b);
}

// ---------------------------------------------------------------------------
// Generic  C[M,N] = epilogue(A[M,256] @ B[N,256]^T)   (bf16 in, MFMA 16x16x32)
// 128x128 tile, BK=64, 4 waves (2x2), XOR-swizzled LDS (16B chunk ^ row&7).
// EPI 0: +biascat, relu for cols<512, route {0:k,1:v,2:q2-strided} bf16
// EPI 1: +bias, relu, bf16 out [M,256]
// EPI 2: *scale, bf16 out ld=65536
// ---------------------------------------------------------------------------
template <int EPI>
__global__ __launch_bounds__(256, 2)
void gemm_bt(const u16* __restrict__ A, const u16* __restrict__ B,
             const float* __restrict__ bias, float scale,
             u16* __restrict__ ob0, u16* __restrict__ ob1, u16* __restrict__ ob2,
             float* __restrict__ of) {
  __shared__ __align__(16) u16 As[128 * 64];
  __shared__ __align__(16) u16 Bs[128 * 64];
  const int tid = threadIdx.x;
  const int lane = tid & 63;
  const int l15 = lane & 15;
  const int l4 = lane >> 4;
  const int wid = tid >> 6;
  const int wm = wid >> 1, wn = wid & 1;
  const long m0 = (long)blockIdx.y * 128;
  const long n0 = (long)blockIdx.x * 128;

  v4f acc[4][4] = {};

  for (int kb = 0; kb < 256; kb += 64) {
    __syncthreads();
#pragma unroll
    for (int i = 0; i < 4; i++) {
      int cid = tid + 256 * i;          // 1024 16B-chunks per tile
      int row = cid >> 3, ch = cid & 7; // 8 chunks per 64-col row
      int sch = ch ^ (row & 7);
      uint4 da = *reinterpret_cast<const uint4*>(A + (m0 + row) * 256 + kb + ch * 8);
      *reinterpret_cast<uint4*>(&As[row * 64 + sch * 8]) = da;
      uint4 db = *reinterpret_cast<const uint4*>(B + (n0 + row) * 256 + kb + ch * 8);
      *reinterpret_cast<uint4*>(&Bs[row * 64 + sch * 8]) = db;
    }
    __syncthreads();
#pragma unroll
    for (int ks = 0; ks < 2; ks++) {
      v8bf af[4], bfr[4];
#pragma unroll
      for (int m = 0; m < 4; m++) {
        int row = wm * 64 + m * 16 + l15;
        int sch = (ks * 4 + l4) ^ (row & 7);
        af[m] = *reinterpret_cast<const v8bf*>(&As[row * 64 + sch * 8]);
      }
#pragma unroll
      for (int n = 0; n < 4; n++) {
        int row = wn * 64 + n * 16 + l15;
        int sch = (ks * 4 + l4) ^ (row & 7);
        bfr[n] = *reinterpret_cast<const v8bf*>(&Bs[row * 64 + sch * 8]);
      }
#pragma unroll
      for (int m = 0; m < 4; m++)
#pragma unroll
        for (int n = 0; n < 4; n++)
          acc[m][n] = __builtin_amdgcn_mfma_f32_16x16x32_bf16(af[m], bfr[n], acc[m][n], 0, 0, 0);
    }
  }

  const int r4 = l4 * 4;
#pragma unroll
  for (int m = 0; m < 4; m++) {
#pragma unroll
    for (int n = 0; n < 4; n++) {
#pragma unroll
      for (int r = 0; r < 4; r++) {
        long grow = m0 + wm * 64 + m * 16 + r4 + r;
        long gcol = n0 + wn * 64 + n * 16 + l15;
        float v = acc[m][n][r];
        if constexpr (EPI == 0) {
          v += bias[gcol];
          int which = (int)(gcol >> 8);
          long jj = gcol & 255;
          if (which < 2) v = fmaxf(v, 0.f);
          u16 hv = f2b(v);
          if (which == 0) ob0[grow * 256 + jj] = hv;
          else if (which == 1) ob1[grow * 256 + jj] = hv;
          else ob2[(grow & ~31L) * 2048 + (grow & 31) * 256 + jj] = hv;  // q2 strided
        } else if constexpr (EPI == 1) {
          v += bias[gcol];
          v = fmaxf(v, 0.f);
          ob0[grow * 256 + gcol] = f2b(v);
        } else if constexpr (EPI == 2) {
          ob0[grow * 65536 + gcol] = f2b(v * scale);
        } else {
          of[grow * 1024 + gcol] = v * scale;
        }
      }
    }
  }
}

// ---------------------------------------------------------------------------
// Weight prep: Wcat^T bf16 [768,256] rows = [wk cols | wv cols | wq cols]
// ---------------------------------------------------------------------------
__global__ __launch_bounds__(256)
void prep_w_kernel(const float* __restrict__ wq, const float* __restrict__ wk,
                   const float* __restrict__ wv, const float* __restrict__ bq,
                   const float* __restrict__ bk, const float* __restrict__ bv,
                   u16* __restrict__ wcat, float* __restrict__ bcat) {
  int n = blockIdx.x;
  int t = threadIdx.x;
  const float* W = (n < 256) ? wk : (n < 512) ? wv : wq;
  int jj = n & 255;
  wcat[n * 256 + t] = f2b(W[t * 256 + jj]);
  if (t == 0) {
    const float* Bb = (n < 256) ? bk : (n < 512) ? bv : bq;
    bcat[n] = Bb[jj];
  }
}

// ---------------------------------------------------------------------------
// x = LayerNorm(inputs) -> bf16.  One wave per row (4 f32 per lane).
// ---------------------------------------------------------------------------
__global__ __launch_bounds__(256)
void ln_x_kernel(const float* __restrict__ x, const float* __restrict__ lw,
                 const float* __restrict__ lb, u16* __restrict__ out) {
  const int lane = threadIdx.x & 63, wid = threadIdx.x >> 6;
  const long row = (long)blockIdx.x * 4 + wid;
  float4 v = reinterpret_cast<const float4*>(x + row * 256)[lane];
  float s = v.x + v.y + v.z + v.w;
  for (int sh = 1; sh < 64; sh <<= 1) s += __shfl_xor(s, sh);
  float mu = s * (1.f / 256.f);
  float dx = v.x - mu, dy = v.y - mu, dz = v.z - mu, dw = v.w - mu;
  float q = dx * dx + dy * dy + dz * dz + dw * dw;
  for (int sh = 1; sh < 64; sh <<= 1) q += __shfl_xor(q, sh);
  float rs = rsqrtf(q * (1.f / 256.f) + 1e-5f);
  float4 wv = reinterpret_cast<const float4*>(lw)[lane];
  float4 bv = reinterpret_cast<const float4*>(lb)[lane];
  ushort4 o4;
  o4.x = f2b(dx * rs * wv.x + bv.x);
  o4.y = f2b(dy * rs * wv.y + bv.y);
  o4.z = f2b(dz * rs * wv.z + bv.z);
  o4.w = f2b(dw * rs * wv.w + bv.w);
  reinterpret_cast<ushort4*>(out + row * 256)[lane] = o4;
}

// ---------------------------------------------------------------------------
// edges = mu + exp(ls)*noise ; e = LayerNorm(edges) -> f32 + bf16
// ---------------------------------------------------------------------------
__global__ __launch_bounds__(256)
void edges_e_kernel(const float* __restrict__ noise, const float* __restrict__ emu,
                    const float* __restrict__ els, const float* __restrict__ lw,
                    const float* __restrict__ lb, float* __restrict__ e_f,
                    u16* __restrict__ e_b) {
  const int lane = threadIdx.x & 63, wid = threadIdx.x >> 6;
  const long row = (long)blockIdx.x * 4 + wid;
  float4 nz = reinterpret_cast<const float4*>(noise + row * 256)[lane];
  float4 mu4 = reinterpret_cast<const float4*>(emu)[lane];
  float4 ls4 = reinterpret_cast<const float4*>(els)[lane];
  float4 ed;
  ed.x = mu4.x + expf(ls4.x) * nz.x;
  ed.y = mu4.y + expf(ls4.y) * nz.y;
  ed.z = mu4.z + expf(ls4.z) * nz.z;
  ed.w = mu4.w + expf(ls4.w) * nz.w;
  float s = ed.x + ed.y + ed.z + ed.w;
  for (int sh = 1; sh < 64; sh <<= 1) s += __shfl_xor(s, sh);
  float mu = s * (1.f / 256.f);
  float dx = ed.x - mu, dy = ed.y - mu, dz = ed.z - mu, dw = ed.w - mu;
  float qv = dx * dx + dy * dy + dz * dz + dw * dw;
  for (int sh = 1; sh < 64; sh <<= 1) qv += __shfl_xor(qv, sh);
  float rs = rsqrtf(qv * (1.f / 256.f) + 1e-5f);
  float4 wv = reinterpret_cast<const float4*>(lw)[lane];
  float4 bv = reinterpret_cast<const float4*>(lb)[lane];
  float4 ef;
  ef.x = dx * rs * wv.x + bv.x;
  ef.y = dy * rs * wv.y + bv.y;
  ef.z = dz * rs * wv.z + bv.z;
  ef.w = dw * rs * wv.w + bv.w;
  reinterpret_cast<float4*>(e_f + row * 256)[lane] = ef;
  ushort4 o4;
  o4.x = f2b(ef.x); o4.y = f2b(ef.y); o4.z = f2b(ef.z); o4.w = f2b(ef.w);
  reinterpret_cast<ushort4*>(e_b + row * 256)[lane] = o4;
}

// ---------------------------------------------------------------------------
// d2d3 v2 (unchanged): one block (256 threads) per q-row, ~27 KB LDS,
// all 1024 blocks co-resident.  3-pass streaming histogram rank-select
// + sparse attn@v gather.  Fixed softmax shift C=8.
// ---------------------------------------------------------------------------
struct D2Shm {
  u32 hist[256 * 16];     // 16 KiB: bin b, copy c at [b*16+c]
  u32 c_hi[256];
  u32 sel_idx[1152];
  float sel_w[1152];
  float fred[4];
  u32 sb_star, sThi, sThr;
  float sSE, sFrac;
  u32 scnt;
};

__global__ __launch_bounds__(256, 5)
void d2d3_kernel(const u16* __restrict__ dots, const u16* __restrict__ vmat,
                 const int* __restrict__ knp, float* __restrict__ upd) {
  __shared__ D2Shm S;
  const int tid = threadIdx.x, lane = tid & 63, wid = tid >> 6;
  const int hc = (lane >> 2);          // 16 lane-indexed histogram copies
  const long r = blockIdx.x;
  const int kn = *knp;

  for (int i = tid; i < 4096; i += 256) S.hist[i] = 0;
  if (tid == 0) S.scnt = 0;
  __syncthreads();

  const float C = 8.f;  // fixed softmax shift (dots >= 0 since q,k relu'd)
  const uint4* src = reinterpret_cast<const uint4*>(dots + r * 65536);

  // ---- pass 1: high-byte histogram + sum-exp ----
  float se = 0.f;
  for (int c = tid; c < 8192; c += 256) {
    uint4 d = src[c];
    u32 h[8] = {d.x & 0xffffu, d.x >> 16, d.y & 0xffffu, d.y >> 16,
                d.z & 0xffffu, d.z >> 16, d.w & 0xffffu, d.w >> 16};
#pragma unroll
    for (int j = 0; j < 8; j++) {
      u32 k = b2k(h[j]);
      se += __expf(b2f((u16)h[j]) - C);
      atomicAdd(&S.hist[(k >> 8) * 16 + hc], 1u);
    }
  }
  for (int sh = 1; sh < 64; sh <<= 1) se += __shfl_xor(se, sh);
  if (lane == 0) S.fred[wid] = se;
  __syncthreads();

  // reduce copies -> c_hi
  {
    u32 s = 0;
#pragma unroll
    for (int c = 0; c < 16; c++) s += S.hist[tid * 16 + c];
    S.c_hi[tid] = s;
  }
  __syncthreads();

  // ---- scan 1: wave 0 -> b*, Thi;  waves 1-3 re-zero hist ----
  if (tid < 64) {
    u32 s = S.c_hi[4 * tid] + S.c_hi[4 * tid + 1] + S.c_hi[4 * tid + 2] + S.c_hi[4 * tid + 3];
    u32 v = s;
    for (int off = 1; off < 64; off <<= 1) {
      u32 t = (u32)__shfl_down((int)v, off);
      if (tid + off < 64) v += t;        // inclusive suffix sum over lanes
    }
    u32 excl = v - s;
    if (v >= (u32)kn && excl < (u32)kn) {
      u32 acc = excl;
#pragma unroll
      for (int bb = 3; bb >= 0; --bb) {
        int b = 4 * tid + bb;
        u32 nb = acc + S.c_hi[b];
        if (nb >= (u32)kn) { S.sb_star = (u32)b; S.sThi = acc; break; }
        acc = nb;
      }
    }
  } else {
    for (int i = tid - 64; i < 4096; i += 192) S.hist[i] = 0;
  }
  __syncthreads();
  const u32 bstar = S.sb_star;

  // ---- pass 2: low-byte histogram within bin b* (row re-read, L3-hot) ----
  for (int c = tid; c < 8192; c += 256) {
    uint4 d = src[c];
    u32 h[8] = {d.x & 0xffffu, d.x >> 16, d.y & 0xffffu, d.y >> 16,
                d.z & 0xffffu, d.z >> 16, d.w & 0xffffu, d.w >> 16};
#pragma unroll
    for (int j = 0; j < 8; j++) {
      u32 k = b2k(h[j]);
      if ((k >> 8) == bstar) atomicAdd(&S.hist[(k & 255u) * 16 + hc], 1u);
    }
  }
  __syncthreads();
  {
    u32 s = 0;
#pragma unroll
    for (int c = 0; c < 16; c++) s += S.hist[tid * 16 + c];
    S.c_hi[tid] = s;
  }
  __syncthreads();

  // ---- scan 2: wave 0 -> exact threshold, tie counts, SE ----
  if (tid < 64) {
    u32 s = S.c_hi[4 * tid] + S.c_hi[4 * tid + 1] + S.c_hi[4 * tid + 2] + S.c_hi[4 * tid + 3];
    u32 v = s;
    for (int off = 1; off < 64; off <<= 1) {
      u32 t = (u32)__shfl_down((int)v, off);
      if (tid + off < 64) v += t;
    }
    const u32 Thi = S.sThi;              // count(high byte > b*)
    u32 incl = v + Thi;
    u32 excl = v - s + Thi;
    if (incl >= (u32)kn && excl < (u32)kn) {
      u32 acc = excl;
#pragma unroll
      for (int bb = 3; bb >= 0; --bb) {
        int b = 4 * tid + bb;
        u32 nb = acc + S.c_hi[b];
        if (nb >= (u32)kn) {
          S.sThr = (bstar << 8) | (u32)b;
          // acc = count(key > thr), c_hi[b] = count(key == thr)
          S.sFrac = (float)(int)((u32)kn - acc) / (float)S.c_hi[b];
          break;
        }
        acc = nb;
      }
    }
    if (tid == 0) {
      float SE = S.fred[0] + S.fred[1] + S.fred[2] + S.fred[3];
      S.sSE = SE;
    }
  }
  __syncthreads();
  const u32 thr = S.sThr;
  const float frac = S.sFrac;
  const float invs = 1.f / S.sSE;
  const float wnorm = 1.f / (1.f + 65536.f * 1e-8f);

  // ---- pass 3: selection: keys >= thr -> (global idx, weight) list ----
  for (int c = tid; c < 8192; c += 256) {
    uint4 d = src[c];
    u32 h[8] = {d.x & 0xffffu, d.x >> 16, d.y & 0xffffu, d.y >> 16,
                d.z & 0xffffu, d.z >> 16, d.w & 0xffffu, d.w >> 16};
#pragma unroll
    for (int j = 0; j < 8; j++) {
      u32 k = b2k(h[j]);
      if (k >= thr) {
        float w = (__expf(k2fv(k) - C) * invs + 1e-8f) * wnorm;
        if (k == thr) w *= frac;
        u32 p = atomicAdd(&S.scnt, 1u);
        if (p < 1152u) { S.sel_idx[p] = (u32)c * 8u + (u32)j; S.sel_w[p] = w; }
      }
    }
  }
  __syncthreads();
  const u32 nsel = S.scnt < 1152u ? S.scnt : 1152u;

  // ---- gather: thread t owns output col t; 4-deep ILP ----
  float a0 = 0.f, a1 = 0.f, a2 = 0.f, a3 = 0.f;
  u32 j = 0;
  for (; j + 3 < nsel; j += 4) {
    a0 = fmaf(S.sel_w[j], b2f(vmat[(long)S.sel_idx[j] * 256 + tid]), a0);
    a1 = fmaf(S.sel_w[j + 1], b2f(vmat[(long)S.sel_idx[j + 1] * 256 + tid]), a1);
    a2 = fmaf(S.sel_w[j + 2], b2f(vmat[(long)S.sel_idx[j + 2] * 256 + tid]), a2);
    a3 = fmaf(S.sel_w[j + 3], b2f(vmat[(long)S.sel_idx[j + 3] * 256 + tid]), a3);
  }
  for (; j < nsel; ++j)
    a0 = fmaf(S.sel_w[j], b2f(vmat[(long)S.sel_idx[j] * 256 + tid]), a0);
  upd[r * 256 + tid] = (a0 + a1) + (a2 + a3);
}

// ---------------------------------------------------------------------------
// mlp: edges_out = relu([e, upd] @ w1 + b1) @ w2 + b2   (f32, one block/row)
// ---------------------------------------------------------------------------
__global__ __launch_bounds__(256)
void mlp_kernel(const float* __restrict__ e, const float* __restrict__ upd,
                const float* __restrict__ w1, const float* __restrict__ b1,
                const float* __restrict__ w2, const float* __restrict__ b2,
                float* __restrict__ eout, u16* __restrict__ eb) {
  __shared__ float ecat[512];
  __shared__ float h[256];
  const int t = threadIdx.x;
  const long r = blockIdx.x;
  ecat[t] = e[r * 256 + t];
  ecat[256 + t] = upd[r * 256 + t];
  __syncthreads();
  float acc = b1[t];
#pragma unroll 8
  for (int kk = 0; kk < 512; ++kk) acc = fmaf(ecat[kk], w1[kk * 256 + t], acc);
  h[t] = fmaxf(acc, 0.f);
  __syncthreads();
  float a2 = b2[t];
#pragma unroll 8
  for (int kk = 0; kk < 256; ++kk) a2 = fmaf(h[kk], w2[kk * 256 + t], a2);
  eout[r * 256 + t] = a2;
  eb[r * 256 + t] = f2b(a2);
}

// ---------------------------------------------------------------------------
// d3h v6 = v3 + asm-pinned afrag.  FUSED dots2 + H at 2 blocks/CU.
// One block = 32 rows, 512 threads, 8 waves as 2M(16 rows) x 4N.
//   phase 1: A(q2) fragments -> registers, then PINNED via asm "+v" so the
//            compiler cannot rematerialize the global loads into the loop
//            (R10's VGPR=36 proved it was doing exactly that).
//   phase 2: 16 col-chunks x 4 kb: stage Bk[64][64] (8 KB), 2 MFMA;
//            acc -> stg (f32) + keys (bf16); coalesced 256 B dots2 writes.
//   phase 3: per-wave top-ke over 4 rows from bf16 keys -> H.
// LDS = keys 64K + stg 8K + Bk 8K = 80 KB -> 2 blocks/CU.
// ---------------------------------------------------------------------------
struct D3HShm {
  u16 keys[32 * 1024];     // 64 KiB bf16 dots2 values
  float stg[32 * 64];      // 8 KiB f32 write-staging (one 64-col stripe)
  u16 Bk[64 * 64];         // 8 KiB
};

__global__ __launch_bounds__(512, 4)
void d3h_kernel(const u16* __restrict__ q2s, const u16* __restrict__ k2,
                const int* __restrict__ kep, float* __restrict__ d2out,
                float* __restrict__ H) {
  extern __shared__ char d3hsm[];
  D3HShm* S = reinterpret_cast<D3HShm*>(d3hsm);
  const int tid = threadIdx.x;
  const int lane = tid & 63;
  const int l15 = lane & 15;
  const int l4 = lane >> 4;
  const int w = tid >> 6;
  const int wm = w >> 2, wn = w & 3;
  const long m0 = (long)blockIdx.x * 32;

  // ---- A fragments into registers, pinned against rematerialization ----
  const u16* q2blk = q2s + m0 * 2048;          // own strided slot
  const int arow = wm * 16 + l15;
  v8bf afrag[8];
#pragma unroll
  for (int kb = 0; kb < 4; kb++)
#pragma unroll
    for (int ks = 0; ks < 2; ks++)
      afrag[kb * 2 + ks] = *reinterpret_cast<const v8bf*>(
          q2blk + arow * 256 + kb * 64 + ks * 32 + l4 * 8);
#pragma unroll
  for (int i = 0; i < 8; i++) asm volatile("" : "+v"(afrag[i]));

  const int brow = wn * 16 + l15;

  // ---- 16 col-chunks of 64 ----
#pragma unroll 1
  for (int nc = 0; nc < 16; nc++) {
    v4f acc = {};
#pragma unroll
    for (int kb = 0; kb < 4; kb++) {
      __syncthreads();                         // also guards stg reuse
      {
        int row = tid >> 3, ch = tid & 7;      // 512 x 16B chunks
        int sch = ch ^ (row & 7);
        uint4 d = *reinterpret_cast<const uint4*>(k2 + (nc * 64 + row) * 256 + kb * 64 + ch * 8);
        *reinterpret_cast<uint4*>(&S->Bk[row * 64 + sch * 8]) = d;
      }
      __syncthreads();
#pragma unroll
      for (int ks = 0; ks < 2; ks++) {
        v8bf b = *reinterpret_cast<const v8bf*>(
            &S->Bk[brow * 64 + (((ks * 4 + l4) ^ (brow & 7))) * 8]);
        acc = __builtin_amdgcn_mfma_f32_16x16x32_bf16(afrag[kb * 2 + ks], b, acc, 0, 0, 0);
      }
    }
    // scale; stash f32 into stg and bf16 into keys
#pragma unroll
    for (int r = 0; r < 4; r++) {
      int lr = wm * 16 + l4 * 4 + r;           // 0..31
      int lc = wn * 16 + l15;                  // 0..63
      float v = acc[r] * 0.0625f;
      S->stg[lr * 64 + lc] = v;
      S->keys[lr * 1024 + nc * 64 + lc] = f2b(v);
    }
    __syncthreads();
    // coalesced dots2 write of this 64-col stripe (256 B segments)
    {
      int row = tid >> 4;                      // 0..31
      int c4 = (tid & 15) * 4;                 // 0..60
      float4 v = *reinterpret_cast<const float4*>(&S->stg[row * 64 + c4]);
      *reinterpret_cast<float4*>(&d2out[(m0 + row) * 1024 + nc * 64 + c4]) = v;
    }
  }
  __syncthreads();

  // ---- top-ke phase: wave w owns rows m0 + w*4 .. +3, from bf16 keys ----
  const int ke = *kep;
#pragma unroll
  for (int j = 0; j < 4; j++) {
    const int lrow = w * 4 + j;
    const long row = m0 + lrow;
    uint4 ka = *reinterpret_cast<const uint4*>(&S->keys[lrow * 1024 + lane * 16]);
    uint4 kb2 = *reinterpret_cast<const uint4*>(&S->keys[lrow * 1024 + lane * 16 + 8]);
    u32 kw[8] = {ka.x, ka.y, ka.z, ka.w, kb2.x, kb2.y, kb2.z, kb2.w};
    u32 k16[16];
    float x[16];
#pragma unroll
    for (int i = 0; i < 8; i++) {
      u32 lo16 = kw[i] & 0xffffu, hi16 = kw[i] >> 16;
      k16[2 * i] = b2k(lo16);     x[2 * i] = b2f((u16)lo16);
      k16[2 * i + 1] = b2k(hi16); x[2 * i + 1] = b2f((u16)hi16);
    }
    float mx = x[0];
#pragma unroll
    for (int i = 1; i < 16; i++) mx = fmaxf(mx, x[i]);
    for (int sh = 1; sh < 64; sh <<= 1) mx = fmaxf(mx, __shfl_xor(mx, sh));
    float p[16];
    float se = 0.f;
#pragma unroll
    for (int i = 0; i < 16; i++) { p[i] = __expf(x[i] - mx); se += p[i]; }
    for (int sh = 1; sh < 64; sh <<= 1) se += __shfl_xor(se, sh);
    const float invs = 1.f / se;
    u32 lo = 0;
    for (int b = 15; b >= 0; --b) {
      u32 t = lo | (1u << b);
      int cnt = 0;
#pragma unroll
      for (int i = 0; i < 16; i++) cnt += (k16[i] >= t);
      for (int sh = 1; sh < 64; sh <<= 1) cnt += __shfl_xor(cnt, sh);
      if (cnt >= ke) lo = t;
    }
    float o[16];
#pragma unroll
    for (int i = 0; i < 16; i++) o[i] = (k16[i] >= lo) ? p[i] * invs : 0.f;
    float4* dst = reinterpret_cast<float4*>(&H[row * 1024 + lane * 16]);
#pragma unroll
    for (int i = 0; i < 4; i++) {
      float4 ov;
      ov.x = o[4 * i]; ov.y = o[4 * i + 1]; ov.z = o[4 * i + 2]; ov.w = o[4 * i + 3];
      dst[i] = ov;
    }
  }
}

// ---------------------------------------------------------------------------
extern "C" void kernel_launch(void* const* d_in, const int* in_sizes, int n_in,
                              void* d_out, int out_size, void* d_ws, size_t ws_size,
                              hipStream_t stream) {
  (void)in_sizes; (void)n_in; (void)out_size; (void)ws_size;

  float* out = (float*)d_out;
  float* out_edges = out;                       // [1024,256]
  float* out_H = out + NSL * DD;                // [65536,1024]
  float* out_d2 = out_H + NN * NSL;             // [65536,1024]

  // H region scratch (every occupant dead before d3h overwrites with H):
  char* Hb = (char*)out_H;
  u16* dots = (u16*)Hb;                          // 134217728 B
  u16* xln = (u16*)(Hb + 134217728L);            // 32 MB
  u16* kb_ = (u16*)(Hb + 167772160L);            // 32 MB
  u16* vb_ = (u16*)(Hb + 201326592L);            // 32 MB
  char* smb = Hb + 234881024L;
  u16* wcat = (u16*)smb;      smb += 768 * 256 * 2;
  float* bcat = (float*)smb;  smb += 4096;
  float* e_f = (float*)smb;   smb += 1024 * 256 * 4;
  u16* e_b = (u16*)smb;       smb += 1024 * 256 * 2;
  u16* q_b = (u16*)smb;       smb += 1024 * 256 * 2;
  float* updf = (float*)smb;  smb += 1024 * 256 * 4;
  u16* edg_b = (u16*)smb;     smb += 1024 * 256 * 2;
  // dots2 region holds the strided q2 tiles (consumed block-locally by d3h).
  u16* q2s = (u16*)out_d2;
  // k2 in workspace (512 KB): the only scratch that must survive into d3h.
  u16* k2ws = (u16*)d_ws;

  hipFuncSetAttribute(reinterpret_cast<const void*>(d3h_kernel),
                      hipFuncAttributeMaxDynamicSharedMemorySize,
                      (int)sizeof(D3HShm));

  prep_w_kernel<<<768, 256, 0, stream>>>(
      (const float*)d_in[4], (const float*)d_in[6], (const float*)d_in[8],
      (const float*)d_in[5], (const float*)d_in[7], (const float*)d_in[9], wcat, bcat);
  edges_e_kernel<<<256, 256, 0, stream>>>(
      (const float*)d_in[1], (const float*)d_in[2], (const float*)d_in[3],
      (const float*)d_in[16], (const float*)d_in[17], e_f, e_b);
  ln_x_kernel<<<16384, 256, 0, stream>>>(
      (const float*)d_in[0], (const float*)d_in[14], (const float*)d_in[15], xln);
  gemm_bt<1><<<dim3(2, 8), 256, 0, stream>>>(e_b, wcat + 512 * 256, bcat + 512, 1.f,
                                             q_b, nullptr, nullptr, nullptr);
  gemm_bt<0><<<dim3(6, 512), 256, 0, stream>>>(xln, wcat, bcat, 1.f,
                                               kb_, vb_, q2s, nullptr);
  gemm_bt<2><<<dim3(512, 8), 256, 0, stream>>>(q_b, kb_, nullptr, 0.0625f,
                                               dots, nullptr, nullptr, nullptr);
  d2d3_kernel<<<1024, 256, 0, stream>>>(dots, vb_, (const int*)d_in[18], updf);
  mlp_kernel<<<1024, 256, 0, stream>>>(e_f, updf,
                                       (const float*)d_in[10], (const float*)d_in[11],
                                       (const float*)d_in[12], (const float*)d_in[13],
                                       out_edges, edg_b);
  gemm_bt<1><<<dim3(2, 8), 256, 0, stream>>>(edg_b, wcat, bcat, 1.f,
                                             k2ws, nullptr, nullptr, nullptr);
  d3h_kernel<<<2048, 512, sizeof(D3HShm), stream>>>(q2s, k2ws, (const int*)d_in[19],
                                                    out_d2, out_H);
}

// Round 14
// 628.199 us; speedup vs baseline: 1.1913x; 1.0262x over previous
//
#include <hip/hip_runtime.h>
#include <hip/hip_bf16.h>
#include <stdint.h>

// ---------------------------------------------------------------------------
// HConstructor: slot-attention-like block on MI355X.
//   inputs [65536,256], noise [1024,256] -> edges [1024,256], H [65536,1024],
//   dots2 [65536,1024].
// Pipeline (all on `stream`):
//   prep_w   : Wcat^T = [wk|wv|wq]^T as bf16 [768,256], bias cat
//   edges_e  : edges = mu + exp(ls)*noise ; e = LN(edges)  (f32 + bf16)
//   ln_x     : x = LN(inputs) -> bf16 [65536,256]
//   gemm<1>  : q  = relu(e @ wq + bq)           [1024,256]  bf16
//   gemm<0>  : k,v = relu(x@wk/v + b), q2 = x@wq+bq (normal layout, H-region)
//   gemm<2>  : dots = (q @ k^T) * 1/16 -> bf16 [1024,65536] (H-region scratch)
//   d2d3 v2  : 3-pass streaming rank-select (~53 us measured).
//   mlp      : edges_out = relu([e,upd]@w1+b1)@w2+b2 -> OUT + bf16
//   gemm<1>  : k2 = relu(edges_out @ wk + bk) -> d_ws (512 KB)
//   gemm<3>  : dots2 = (q2 @ k2^T) * 1/16 -> OUT f32       } SPLIT pair,
//   g2       : H = softmax(dots2) * top32-mask -> OUT      } ~195 us
//
// LEDGER (hard A/B, X = pipeline minus d2d3 minus dots2/H phase = 291 us):
//   dots2/H phase: SPLIT gemm<3>+g2 = 195  <-- this file
//                  fused v3/v6 = 301, v4 = 308, v5 = 404, R7 = 410, R8 = 623
//   Every fusion lost: the split runs both halves at high occupancy with
//   pure streaming; fusion traded that for traffic that L3 already absorbed.
// Scratch map:
//   H region   : dots(134M) | q2b(32M) | smalls(~4M)   (dead before g2 -> H)
//   dots2 reg. : xln(32M) | kb(32M) | vb(32M)          (dead before gemm<3>)
//   d_ws       : k2 bf16 (512 KB)
// ---------------------------------------------------------------------------

#define DEV __device__ __forceinline__

typedef uint32_t u32;
typedef uint16_t u16;
typedef __bf16 v8bf __attribute__((ext_vector_type(8)));
typedef float v4f __attribute__((ext_vector_type(4)));

static constexpr long NN = 65536;
static constexpr long DD = 256;
static constexpr long NSL = 1024;

DEV u16 f2b(float f) {
  u32 u = __builtin_bit_cast(u32, f);
  u32 r = (u + 0x7FFFu + ((u >> 16) & 1u)) >> 16;
  return (u16)r;
}
DEV float b2f(u16 h) { u32 u = ((u32)h) << 16; return __builtin_bit_cast(float, u); }
// bf16 bits (as u32 low16) -> monotone sortable 16-bit key
DEV u32 b2k(u32 b) { return b ^ (0x8000u + 0x7FFFu * (b >> 15)); }
DEV float k2fv(u32 k) {
  u16 b = (k & 0x8000u) ? (u16)(k ^ 0x8000u) : (u16)(k ^ 0xFFFFu);
  return b2f(b);
}

// ---------------------------------------------------------------------------
// Generic  C[M,N] = epilogue(A[M,256] @ B[N,256]^T)   (bf16 in, MFMA 16x16x32)
// 128x128 tile, BK=64, 4 waves (2x2), XOR-swizzled LDS (16B chunk ^ row&7).
// EPI 0: +biascat, relu for cols<512, route cols {0:k,1:v,2:q2} bf16 [M,256]
// EPI 1: +bias, relu, bf16 out [M,256]
// EPI 2: *scale, bf16 out ld=65536
// EPI 3: *scale, f32 out ld=1024
// ---------------------------------------------------------------------------
template <int EPI>
__global__ __launch_bounds__(256, 2)
void gemm_bt(const u16* __restrict__ A, const u16* __restrict__ B,
             const float* __restrict__ bias, float scale,
             u16* __restrict__ ob0, u16* __restrict__ ob1, u16* __restrict__ ob2,
             float* __restrict__ of) {
  __shared__ __align__(16) u16 As[128 * 64];
  __shared__ __align__(16) u16 Bs[128 * 64];
  const int tid = threadIdx.x;
  const int lane = tid & 63;
  const int l15 = lane & 15;
  const int l4 = lane >> 4;
  const int wid = tid >> 6;
  const int wm = wid >> 1, wn = wid & 1;
  const long m0 = (long)blockIdx.y * 128;
  const long n0 = (long)blockIdx.x * 128;

  v4f acc[4][4] = {};

  for (int kb = 0; kb < 256; kb += 64) {
    __syncthreads();
#pragma unroll
    for (int i = 0; i < 4; i++) {
      int cid = tid + 256 * i;          // 1024 16B-chunks per tile
      int row = cid >> 3, ch = cid & 7; // 8 chunks per 64-col row
      int sch = ch ^ (row & 7);
      uint4 da = *reinterpret_cast<const uint4*>(A + (m0 + row) * 256 + kb + ch * 8);
      *reinterpret_cast<uint4*>(&As[row * 64 + sch * 8]) = da;
      uint4 db = *reinterpret_cast<const uint4*>(B + (n0 + row) * 256 + kb + ch * 8);
      *reinterpret_cast<uint4*>(&Bs[row * 64 + sch * 8]) = db;
    }
    __syncthreads();
#pragma unroll
    for (int ks = 0; ks < 2; ks++) {
      v8bf af[4], bfr[4];
#pragma unroll
      for (int m = 0; m < 4; m++) {
        int row = wm * 64 + m * 16 + l15;
        int sch = (ks * 4 + l4) ^ (row & 7);
        af[m] = *reinterpret_cast<const v8bf*>(&As[row * 64 + sch * 8]);
      }
#pragma unroll
      for (int n = 0; n < 4; n++) {
        int row = wn * 64 + n * 16 + l15;
        int sch = (ks * 4 + l4) ^ (row & 7);
        bfr[n] = *reinterpret_cast<const v8bf*>(&Bs[row * 64 + sch * 8]);
      }
#pragma unroll
      for (int m = 0; m < 4; m++)
#pragma unroll
        for (int n = 0; n < 4; n++)
          acc[m][n] = __builtin_amdgcn_mfma_f32_16x16x32_bf16(af[m], bfr[n], acc[m][n], 0, 0, 0);
    }
  }

  const int r4 = l4 * 4;
#pragma unroll
  for (int m = 0; m < 4; m++) {
#pragma unroll
    for (int n = 0; n < 4; n++) {
#pragma unroll
      for (int r = 0; r < 4; r++) {
        long grow = m0 + wm * 64 + m * 16 + r4 + r;
        long gcol = n0 + wn * 64 + n * 16 + l15;
        float v = acc[m][n][r];
        if constexpr (EPI == 0) {
          v += bias[gcol];
          int which = (int)(gcol >> 8);
          long jj = gcol & 255;
          if (which < 2) v = fmaxf(v, 0.f);
          u16 hv = f2b(v);
          if (which == 0) ob0[grow * 256 + jj] = hv;
          else if (which == 1) ob1[grow * 256 + jj] = hv;
          else ob2[grow * 256 + jj] = hv;
        } else if constexpr (EPI == 1) {
          v += bias[gcol];
          v = fmaxf(v, 0.f);
          ob0[grow * 256 + gcol] = f2b(v);
        } else if constexpr (EPI == 2) {
          ob0[grow * 65536 + gcol] = f2b(v * scale);
        } else {
          of[grow * 1024 + gcol] = v * scale;
        }
      }
    }
  }
}

// ---------------------------------------------------------------------------
// Weight prep: Wcat^T bf16 [768,256] rows = [wk cols | wv cols | wq cols]
// ---------------------------------------------------------------------------
__global__ __launch_bounds__(256)
void prep_w_kernel(const float* __restrict__ wq, const float* __restrict__ wk,
                   const float* __restrict__ wv, const float* __restrict__ bq,
                   const float* __restrict__ bk, const float* __restrict__ bv,
                   u16* __restrict__ wcat, float* __restrict__ bcat) {
  int n = blockIdx.x;
  int t = threadIdx.x;
  const float* W = (n < 256) ? wk : (n < 512) ? wv : wq;
  int jj = n & 255;
  wcat[n * 256 + t] = f2b(W[t * 256 + jj]);
  if (t == 0) {
    const float* Bb = (n < 256) ? bk : (n < 512) ? bv : bq;
    bcat[n] = Bb[jj];
  }
}

// ---------------------------------------------------------------------------
// x = LayerNorm(inputs) -> bf16.  One wave per row (4 f32 per lane).
// ---------------------------------------------------------------------------
__global__ __launch_bounds__(256)
void ln_x_kernel(const float* __restrict__ x, const float* __restrict__ lw,
                 const float* __restrict__ lb, u16* __restrict__ out) {
  const int lane = threadIdx.x & 63, wid = threadIdx.x >> 6;
  const long row = (long)blockIdx.x * 4 + wid;
  float4 v = reinterpret_cast<const float4*>(x + row * 256)[lane];
  float s = v.x + v.y + v.z + v.w;
  for (int sh = 1; sh < 64; sh <<= 1) s += __shfl_xor(s, sh);
  float mu = s * (1.f / 256.f);
  float dx = v.x - mu, dy = v.y - mu, dz = v.z - mu, dw = v.w - mu;
  float q = dx * dx + dy * dy + dz * dz + dw * dw;
  for (int sh = 1; sh < 64; sh <<= 1) q += __shfl_xor(q, sh);
  float rs = rsqrtf(q * (1.f / 256.f) + 1e-5f);
  float4 wv = reinterpret_cast<const float4*>(lw)[lane];
  float4 bv = reinterpret_cast<const float4*>(lb)[lane];
  ushort4 o4;
  o4.x = f2b(dx * rs * wv.x + bv.x);
  o4.y = f2b(dy * rs * wv.y + bv.y);
  o4.z = f2b(dz * rs * wv.z + bv.z);
  o4.w = f2b(dw * rs * wv.w + bv.w);
  reinterpret_cast<ushort4*>(out + row * 256)[lane] = o4;
}

// ---------------------------------------------------------------------------
// edges = mu + exp(ls)*noise ; e = LayerNorm(edges) -> f32 + bf16
// ---------------------------------------------------------------------------
__global__ __launch_bounds__(256)
void edges_e_kernel(const float* __restrict__ noise, const float* __restrict__ emu,
                    const float* __restrict__ els, const float* __restrict__ lw,
                    const float* __restrict__ lb, float* __restrict__ e_f,
                    u16* __restrict__ e_b) {
  const int lane = threadIdx.x & 63, wid = threadIdx.x >> 6;
  const long row = (long)blockIdx.x * 4 + wid;
  float4 nz = reinterpret_cast<const float4*>(noise + row * 256)[lane];
  float4 mu4 = reinterpret_cast<const float4*>(emu)[lane];
  float4 ls4 = reinterpret_cast<const float4*>(els)[lane];
  float4 ed;
  ed.x = mu4.x + expf(ls4.x) * nz.x;
  ed.y = mu4.y + expf(ls4.y) * nz.y;
  ed.z = mu4.z + expf(ls4.z) * nz.z;
  ed.w = mu4.w + expf(ls4.w) * nz.w;
  float s = ed.x + ed.y + ed.z + ed.w;
  for (int sh = 1; sh < 64; sh <<= 1) s += __shfl_xor(s, sh);
  float mu = s * (1.f / 256.f);
  float dx = ed.x - mu, dy = ed.y - mu, dz = ed.z - mu, dw = ed.w - mu;
  float qv = dx * dx + dy * dy + dz * dz + dw * dw;
  for (int sh = 1; sh < 64; sh <<= 1) qv += __shfl_xor(qv, sh);
  float rs = rsqrtf(qv * (1.f / 256.f) + 1e-5f);
  float4 wv = reinterpret_cast<const float4*>(lw)[lane];
  float4 bv = reinterpret_cast<const float4*>(lb)[lane];
  float4 ef;
  ef.x = dx * rs * wv.x + bv.x;
  ef.y = dy * rs * wv.y + bv.y;
  ef.z = dz * rs * wv.z + bv.z;
  ef.w = dw * rs * wv.w + bv.w;
  reinterpret_cast<float4*>(e_f + row * 256)[lane] = ef;
  ushort4 o4;
  o4.x = f2b(ef.x); o4.y = f2b(ef.y); o4.z = f2b(ef.z); o4.w = f2b(ef.w);
  reinterpret_cast<ushort4*>(e_b + row * 256)[lane] = o4;
}

// ---------------------------------------------------------------------------
// d2d3 v2 (unchanged; ~53us measured): one block (256 threads) per q-row,
// ~27 KB LDS, all 1024 blocks co-resident.  3-pass streaming histogram
// rank-select + sparse attn@v gather.  Fixed softmax shift C=8.
// ---------------------------------------------------------------------------
struct D2Shm {
  u32 hist[256 * 16];     // 16 KiB: bin b, copy c at [b*16+c]
  u32 c_hi[256];
  u32 sel_idx[1152];
  float sel_w[1152];
  float fred[4];
  u32 sb_star, sThi, sThr;
  float sSE, sFrac;
  u32 scnt;
};

__global__ __launch_bounds__(256, 5)
void d2d3_kernel(const u16* __restrict__ dots, const u16* __restrict__ vmat,
                 const int* __restrict__ knp, float* __restrict__ upd) {
  __shared__ D2Shm S;
  const int tid = threadIdx.x, lane = tid & 63, wid = tid >> 6;
  const int hc = (lane >> 2);          // 16 lane-indexed histogram copies
  const long r = blockIdx.x;
  const int kn = *knp;

  for (int i = tid; i < 4096; i += 256) S.hist[i] = 0;
  if (tid == 0) S.scnt = 0;
  __syncthreads();

  const float C = 8.f;  // fixed softmax shift (dots >= 0 since q,k relu'd)
  const uint4* src = reinterpret_cast<const uint4*>(dots + r * 65536);

  // ---- pass 1: high-byte histogram + sum-exp ----
  float se = 0.f;
  for (int c = tid; c < 8192; c += 256) {
    uint4 d = src[c];
    u32 h[8] = {d.x & 0xffffu, d.x >> 16, d.y & 0xffffu, d.y >> 16,
                d.z & 0xffffu, d.z >> 16, d.w & 0xffffu, d.w >> 16};
#pragma unroll
    for (int j = 0; j < 8; j++) {
      u32 k = b2k(h[j]);
      se += __expf(b2f((u16)h[j]) - C);
      atomicAdd(&S.hist[(k >> 8) * 16 + hc], 1u);
    }
  }
  for (int sh = 1; sh < 64; sh <<= 1) se += __shfl_xor(se, sh);
  if (lane == 0) S.fred[wid] = se;
  __syncthreads();

  // reduce copies -> c_hi
  {
    u32 s = 0;
#pragma unroll
    for (int c = 0; c < 16; c++) s += S.hist[tid * 16 + c];
    S.c_hi[tid] = s;
  }
  __syncthreads();

  // ---- scan 1: wave 0 -> b*, Thi;  waves 1-3 re-zero hist ----
  if (tid < 64) {
    u32 s = S.c_hi[4 * tid] + S.c_hi[4 * tid + 1] + S.c_hi[4 * tid + 2] + S.c_hi[4 * tid + 3];
    u32 v = s;
    for (int off = 1; off < 64; off <<= 1) {
      u32 t = (u32)__shfl_down((int)v, off);
      if (tid + off < 64) v += t;        // inclusive suffix sum over lanes
    }
    u32 excl = v - s;
    if (v >= (u32)kn && excl < (u32)kn) {
      u32 acc = excl;
#pragma unroll
      for (int bb = 3; bb >= 0; --bb) {
        int b = 4 * tid + bb;
        u32 nb = acc + S.c_hi[b];
        if (nb >= (u32)kn) { S.sb_star = (u32)b; S.sThi = acc; break; }
        acc = nb;
      }
    }
  } else {
    for (int i = tid - 64; i < 4096; i += 192) S.hist[i] = 0;
  }
  __syncthreads();
  const u32 bstar = S.sb_star;

  // ---- pass 2: low-byte histogram within bin b* (row re-read, L3-hot) ----
  for (int c = tid; c < 8192; c += 256) {
    uint4 d = src[c];
    u32 h[8] = {d.x & 0xffffu, d.x >> 16, d.y & 0xffffu, d.y >> 16,
                d.z & 0xffffu, d.z >> 16, d.w & 0xffffu, d.w >> 16};
#pragma unroll
    for (int j = 0; j < 8; j++) {
      u32 k = b2k(h[j]);
      if ((k >> 8) == bstar) atomicAdd(&S.hist[(k & 255u) * 16 + hc], 1u);
    }
  }
  __syncthreads();
  {
    u32 s = 0;
#pragma unroll
    for (int c = 0; c < 16; c++) s += S.hist[tid * 16 + c];
    S.c_hi[tid] = s;
  }
  __syncthreads();

  // ---- scan 2: wave 0 -> exact threshold, tie counts, SE ----
  if (tid < 64) {
    u32 s = S.c_hi[4 * tid] + S.c_hi[4 * tid + 1] + S.c_hi[4 * tid + 2] + S.c_hi[4 * tid + 3];
    u32 v = s;
    for (int off = 1; off < 64; off <<= 1) {
      u32 t = (u32)__shfl_down((int)v, off);
      if (tid + off < 64) v += t;
    }
    const u32 Thi = S.sThi;              // count(high byte > b*)
    u32 incl = v + Thi;
    u32 excl = v - s + Thi;
    if (incl >= (u32)kn && excl < (u32)kn) {
      u32 acc = excl;
#pragma unroll
      for (int bb = 3; bb >= 0; --bb) {
        int b = 4 * tid + bb;
        u32 nb = acc + S.c_hi[b];
        if (nb >= (u32)kn) {
          S.sThr = (bstar << 8) | (u32)b;
          // acc = count(key > thr), c_hi[b] = count(key == thr)
          S.sFrac = (float)(int)((u32)kn - acc) / (float)S.c_hi[b];
          break;
        }
        acc = nb;
      }
    }
    if (tid == 0) {
      float SE = S.fred[0] + S.fred[1] + S.fred[2] + S.fred[3];
      S.sSE = SE;
    }
  }
  __syncthreads();
  const u32 thr = S.sThr;
  const float frac = S.sFrac;
  const float invs = 1.f / S.sSE;
  const float wnorm = 1.f / (1.f + 65536.f * 1e-8f);

  // ---- pass 3: selection: keys >= thr -> (global idx, weight) list ----
  for (int c = tid; c < 8192; c += 256) {
    uint4 d = src[c];
    u32 h[8] = {d.x & 0xffffu, d.x >> 16, d.y & 0xffffu, d.y >> 16,
                d.z & 0xffffu, d.z >> 16, d.w & 0xffffu, d.w >> 16};
#pragma unroll
    for (int j = 0; j < 8; j++) {
      u32 k = b2k(h[j]);
      if (k >= thr) {
        float w = (__expf(k2fv(k) - C) * invs + 1e-8f) * wnorm;
        if (k == thr) w *= frac;
        u32 p = atomicAdd(&S.scnt, 1u);
        if (p < 1152u) { S.sel_idx[p] = (u32)c * 8u + (u32)j; S.sel_w[p] = w; }
      }
    }
  }
  __syncthreads();
  const u32 nsel = S.scnt < 1152u ? S.scnt : 1152u;

  // ---- gather: thread t owns output col t; 4-deep ILP ----
  float a0 = 0.f, a1 = 0.f, a2 = 0.f, a3 = 0.f;
  u32 j = 0;
  for (; j + 3 < nsel; j += 4) {
    a0 = fmaf(S.sel_w[j], b2f(vmat[(long)S.sel_idx[j] * 256 + tid]), a0);
    a1 = fmaf(S.sel_w[j + 1], b2f(vmat[(long)S.sel_idx[j + 1] * 256 + tid]), a1);
    a2 = fmaf(S.sel_w[j + 2], b2f(vmat[(long)S.sel_idx[j + 2] * 256 + tid]), a2);
    a3 = fmaf(S.sel_w[j + 3], b2f(vmat[(long)S.sel_idx[j + 3] * 256 + tid]), a3);
  }
  for (; j < nsel; ++j)
    a0 = fmaf(S.sel_w[j], b2f(vmat[(long)S.sel_idx[j] * 256 + tid]), a0);
  upd[r * 256 + tid] = (a0 + a1) + (a2 + a3);
}

// ---------------------------------------------------------------------------
// mlp: edges_out = relu([e, upd] @ w1 + b1) @ w2 + b2   (f32, one block/row)
// ---------------------------------------------------------------------------
__global__ __launch_bounds__(256)
void mlp_kernel(const float* __restrict__ e, const float* __restrict__ upd,
                const float* __restrict__ w1, const float* __restrict__ b1,
                const float* __restrict__ w2, const float* __restrict__ b2,
                float* __restrict__ eout, u16* __restrict__ eb) {
  __shared__ float ecat[512];
  __shared__ float h[256];
  const int t = threadIdx.x;
  const long r = blockIdx.x;
  ecat[t] = e[r * 256 + t];
  ecat[256 + t] = upd[r * 256 + t];
  __syncthreads();
  float acc = b1[t];
#pragma unroll 8
  for (int kk = 0; kk < 512; ++kk) acc = fmaf(ecat[kk], w1[kk * 256 + t], acc);
  h[t] = fmaxf(acc, 0.f);
  __syncthreads();
  float a2 = b2[t];
#pragma unroll 8
  for (int kk = 0; kk < 256; ++kk) a2 = fmaf(h[kk], w2[kk * 256 + t], a2);
  eout[r * 256 + t] = a2;
  eb[r * 256 + t] = f2b(a2);
}

// ---------------------------------------------------------------------------
// g2 (R6 split version): per row of dots2 [65536,1024]: softmax, top-ke
// mask, write H.  One wave per row, 16 f32/lane, 32-step binary search on
// f32 monotone key.
// ---------------------------------------------------------------------------
__global__ __launch_bounds__(256)
void g2_kernel(const float* __restrict__ d2, const int* __restrict__ kep,
               float* __restrict__ H) {
  const int lane = threadIdx.x & 63, wid = threadIdx.x >> 6;
  const long row = (long)blockIdx.x * 4 + wid;
  const int ke = *kep;
  const float4* src = reinterpret_cast<const float4*>(d2 + row * 1024);
  float4 q0 = src[lane], q1 = src[64 + lane], q2v = src[128 + lane], q3 = src[192 + lane];
  float x[16] = {q0.x, q0.y, q0.z, q0.w, q1.x, q1.y, q1.z, q1.w,
                 q2v.x, q2v.y, q2v.z, q2v.w, q3.x, q3.y, q3.z, q3.w};
  float mx = x[0];
#pragma unroll
  for (int i = 1; i < 16; i++) mx = fmaxf(mx, x[i]);
  for (int sh = 1; sh < 64; sh <<= 1) mx = fmaxf(mx, __shfl_xor(mx, sh));
  float p[16];
  float se = 0.f;
#pragma unroll
  for (int i = 0; i < 16; i++) { p[i] = __expf(x[i] - mx); se += p[i]; }
  for (int sh = 1; sh < 64; sh <<= 1) se += __shfl_xor(se, sh);
  const float invs = 1.f / se;
  u32 key[16];
#pragma unroll
  for (int i = 0; i < 16; i++) {
    u32 u = __builtin_bit_cast(u32, x[i]);
    key[i] = u ^ ((u >> 31) ? 0xFFFFFFFFu : 0x80000000u);
  }
  u32 lo = 0;
  for (int b = 31; b >= 0; --b) {
    u32 t = lo | (1u << b);
    int cnt = 0;
#pragma unroll
    for (int i = 0; i < 16; i++) cnt += (key[i] >= t);
    for (int sh = 1; sh < 64; sh <<= 1) cnt += __shfl_xor(cnt, sh);
    if (cnt >= ke) lo = t;
  }
  float4 o0, o1, o2, o3;
  o0.x = key[0] >= lo ? p[0] * invs : 0.f;
  o0.y = key[1] >= lo ? p[1] * invs : 0.f;
  o0.z = key[2] >= lo ? p[2] * invs : 0.f;
  o0.w = key[3] >= lo ? p[3] * invs : 0.f;
  o1.x = key[4] >= lo ? p[4] * invs : 0.f;
  o1.y = key[5] >= lo ? p[5] * invs : 0.f;
  o1.z = key[6] >= lo ? p[6] * invs : 0.f;
  o1.w = key[7] >= lo ? p[7] * invs : 0.f;
  o2.x = key[8] >= lo ? p[8] * invs : 0.f;
  o2.y = key[9] >= lo ? p[9] * invs : 0.f;
  o2.z = key[10] >= lo ? p[10] * invs : 0.f;
  o2.w = key[11] >= lo ? p[11] * invs : 0.f;
  o3.x = key[12] >= lo ? p[12] * invs : 0.f;
  o3.y = key[13] >= lo ? p[13] * invs : 0.f;
  o3.z = key[14] >= lo ? p[14] * invs : 0.f;
  o3.w = key[15] >= lo ? p[15] * invs : 0.f;
  float4* dst = reinterpret_cast<float4*>(H + row * 1024);
  dst[lane] = o0;
  dst[64 + lane] = o1;
  dst[128 + lane] = o2;
  dst[192 + lane] = o3;
}

// ---------------------------------------------------------------------------
extern "C" void kernel_launch(void* const* d_in, const int* in_sizes, int n_in,
                              void* d_out, int out_size, void* d_ws, size_t ws_size,
                              hipStream_t stream) {
  (void)in_sizes; (void)n_in; (void)out_size; (void)ws_size;

  float* out = (float*)d_out;
  float* out_edges = out;                       // [1024,256]
  float* out_H = out + NSL * DD;                // [65536,1024]
  float* out_d2 = out_H + NN * NSL;             // [65536,1024]

  // H region scratch (dead before g2 overwrites with H):
  char* Hb = (char*)out_H;
  u16* dots = (u16*)Hb;                          // 134217728 B
  u16* q2b = (u16*)(Hb + 134217728L);            // 32 MB
  char* smb = Hb + 167772160L;
  u16* wcat = (u16*)smb;      smb += 768 * 256 * 2;
  float* bcat = (float*)smb;  smb += 4096;
  float* e_f = (float*)smb;   smb += 1024 * 256 * 4;
  u16* e_b = (u16*)smb;       smb += 1024 * 256 * 2;
  u16* q_b = (u16*)smb;       smb += 1024 * 256 * 2;
  float* updf = (float*)smb;  smb += 1024 * 256 * 4;
  u16* edg_b = (u16*)smb;     smb += 1024 * 256 * 2;
  // dots2 region: xln, k, v bf16 (32MB each); dead before gemm<3> overwrites.
  char* Db = (char*)out_d2;
  u16* xln = (u16*)Db;
  u16* kb_ = (u16*)(Db + 33554432L);
  u16* vb_ = (u16*)(Db + 67108864L);
  // k2 in workspace (512 KB).
  u16* k2ws = (u16*)d_ws;

  prep_w_kernel<<<768, 256, 0, stream>>>(
      (const float*)d_in[4], (const float*)d_in[6], (const float*)d_in[8],
      (const float*)d_in[5], (const float*)d_in[7], (const float*)d_in[9], wcat, bcat);
  edges_e_kernel<<<256, 256, 0, stream>>>(
      (const float*)d_in[1], (const float*)d_in[2], (const float*)d_in[3],
      (const float*)d_in[16], (const float*)d_in[17], e_f, e_b);
  ln_x_kernel<<<16384, 256, 0, stream>>>(
      (const float*)d_in[0], (const float*)d_in[14], (const float*)d_in[15], xln);
  gemm_bt<1><<<dim3(2, 8), 256, 0, stream>>>(e_b, wcat + 512 * 256, bcat + 512, 1.f,
                                             q_b, nullptr, nullptr, nullptr);
  gemm_bt<0><<<dim3(6, 512), 256, 0, stream>>>(xln, wcat, bcat, 1.f,
                                               kb_, vb_, q2b, nullptr);
  gemm_bt<2><<<dim3(512, 8), 256, 0, stream>>>(q_b, kb_, nullptr, 0.0625f,
                                               dots, nullptr, nullptr, nullptr);
  d2d3_kernel<<<1024, 256, 0, stream>>>(dots, vb_, (const int*)d_in[18], updf);
  mlp_kernel<<<1024, 256, 0, stream>>>(e_f, updf,
                                       (const float*)d_in[10], (const float*)d_in[11],
                                       (const float*)d_in[12], (const float*)d_in[13],
                                       out_edges, edg_b);
  gemm_bt<1><<<dim3(2, 8), 256, 0, stream>>>(edg_b, wcat, bcat, 1.f,
                                             k2ws, nullptr, nullptr, nullptr);
  gemm_bt<3><<<dim3(8, 512), 256, 0, stream>>>(q2b, k2ws, nullptr, 0.0625f,
                                               nullptr, nullptr, nullptr, out_d2);
  g2_kernel<<<16384, 256, 0, stream>>>(out_d2, (const int*)d_in[19], out_H);
}

// Round 15
// 594.490 us; speedup vs baseline: 1.2589x; 1.0567x over previous
//
#include <hip/hip_runtime.h>
#include <hip/hip_bf16.h>
#include <stdint.h>

// ---------------------------------------------------------------------------
// HConstructor: slot-attention-like block on MI355X.
//   inputs [65536,256], noise [1024,256] -> edges [1024,256], H [65536,1024],
//   dots2 [65536,1024].
// Pipeline (all on `stream`):
//   prep_w   : Wcat^T = [wk|wv|wq]^T as bf16 [768,256], bias cat
//   edges_e  : edges = mu + exp(ls)*noise ; e = LN(edges)  (f32 + bf16)
//   ln_x     : x = LN(inputs) -> bf16 [65536,256]
//   gemm<1>  : q  = relu(e @ wq + bq)           [1024,256]  bf16
//   gemm<0>  : k,v = relu(x@wk/v + b), q2 = x@wq+bq (normal layout, H-region)
//   gemm<2>  : dots = (q @ k^T) * 1/16 -> bf16 [1024,65536] (H-region scratch)
//   d2d3 v2  : 3-pass streaming rank-select (~155 us corrected estimate).
//   mlp      : edges_out = relu([e,upd]@w1+b1)@w2+b2 -> OUT + bf16
//   gemm<1>  : k2 = relu(edges_out @ wk + bk) -> d_ws (512 KB)
//   gemm<3>  : dots2 = (q2 @ k2^T) * 1/16 -> OUT f32       } SPLIT pair,
//   g2       : H = softmax(dots2) * top32-mask -> OUT      } ~284 us
//
// LEDGER (measured single-variable deltas only):
//   rest(no dots2/H phase) = 344  (X ~189 + d2d3v2 ~155)
//   dots2/H: split = 284 < fused v3 = 301 < v4 = 308 < v5 = 404 < R8 = 623
// R15 change: gemm_bt staging -> __builtin_amdgcn_global_load_lds width=16
//   with PRE-SWIZZLED GLOBAL SOURCE (LDS dest linear per m104/m108; XOR is
//   an involution so LDS contents are identical; fragment reads untouched).
// Scratch map:
//   H region   : dots(134M) | q2b(32M) | smalls(~4M)   (dead before g2 -> H)
//   dots2 reg. : xln(32M) | kb(32M) | vb(32M)          (dead before gemm<3>)
//   d_ws       : k2 bf16 (512 KB)
// ---------------------------------------------------------------------------

#define DEV __device__ __forceinline__

typedef uint32_t u32;
typedef uint16_t u16;
typedef __bf16 v8bf __attribute__((ext_vector_type(8)));
typedef float v4f __attribute__((ext_vector_type(4)));

static constexpr long NN = 65536;
static constexpr long DD = 256;
static constexpr long NSL = 1024;

DEV u16 f2b(float f) {
  u32 u = __builtin_bit_cast(u32, f);
  u32 r = (u + 0x7FFFu + ((u >> 16) & 1u)) >> 16;
  return (u16)r;
}
DEV float b2f(u16 h) { u32 u = ((u32)h) << 16; return __builtin_bit_cast(float, u); }
// bf16 bits (as u32 low16) -> monotone sortable 16-bit key
DEV u32 b2k(u32 b) { return b ^ (0x8000u + 0x7FFFu * (b >> 15)); }
DEV float k2fv(u32 k) {
  u16 b = (k & 0x8000u) ? (u16)(k ^ 0x8000u) : (u16)(k ^ 0xFFFFu);
  return b2f(b);
}

// async global->LDS 16B copy: LDS dest must be wave-linear (base + lane*16).
DEV void gl_lds16(const u16* g, u16* l) {
  __builtin_amdgcn_global_load_lds(
      (const __attribute__((address_space(1))) u32*)g,
      (__attribute__((address_space(3))) u32*)l, 16, 0, 0);
}

// ---------------------------------------------------------------------------
// Generic  C[M,N] = epilogue(A[M,256] @ B[N,256]^T)   (bf16 in, MFMA 16x16x32)
// 128x128 tile, BK=64, 4 waves (2x2).  Staging via global_load_lds width=16:
// LDS layout linear in chunk id; the XOR swizzle (chunk ^ row&7) is applied
// on the GLOBAL SOURCE side (involution -> identical LDS contents to the old
// reg-staged version; fragment reads unchanged).
// EPI 0: +biascat, relu for cols<512, route cols {0:k,1:v,2:q2} bf16 [M,256]
// EPI 1: +bias, relu, bf16 out [M,256]
// EPI 2: *scale, bf16 out ld=65536
// EPI 3: *scale, f32 out ld=1024
// ---------------------------------------------------------------------------
template <int EPI>
__global__ __launch_bounds__(256, 2)
void gemm_bt(const u16* __restrict__ A, const u16* __restrict__ B,
             const float* __restrict__ bias, float scale,
             u16* __restrict__ ob0, u16* __restrict__ ob1, u16* __restrict__ ob2,
             float* __restrict__ of) {
  __shared__ __align__(16) u16 As[128 * 64];
  __shared__ __align__(16) u16 Bs[128 * 64];
  const int tid = threadIdx.x;
  const int lane = tid & 63;
  const int l15 = lane & 15;
  const int l4 = lane >> 4;
  const int wid = tid >> 6;
  const int wm = wid >> 1, wn = wid & 1;
  const long m0 = (long)blockIdx.y * 128;
  const long n0 = (long)blockIdx.x * 128;

  v4f acc[4][4] = {};

  for (int kb = 0; kb < 256; kb += 64) {
    __syncthreads();
#pragma unroll
    for (int i = 0; i < 4; i++) {
      int cid = tid + 256 * i;          // 1024 16B-chunks per tile
      int row = cid >> 3, ch = cid & 7; // 8 chunks per 64-col row
      int sch = ch ^ (row & 7);         // pre-swizzled GLOBAL source chunk
      gl_lds16(A + (m0 + row) * 256 + kb + sch * 8, &As[cid * 8]);
      gl_lds16(B + (n0 + row) * 256 + kb + sch * 8, &Bs[cid * 8]);
    }
    __syncthreads();
#pragma unroll
    for (int ks = 0; ks < 2; ks++) {
      v8bf af[4], bfr[4];
#pragma unroll
      for (int m = 0; m < 4; m++) {
        int row = wm * 64 + m * 16 + l15;
        int sch = (ks * 4 + l4) ^ (row & 7);
        af[m] = *reinterpret_cast<const v8bf*>(&As[row * 64 + sch * 8]);
      }
#pragma unroll
      for (int n = 0; n < 4; n++) {
        int row = wn * 64 + n * 16 + l15;
        int sch = (ks * 4 + l4) ^ (row & 7);
        bfr[n] = *reinterpret_cast<const v8bf*>(&Bs[row * 64 + sch * 8]);
      }
#pragma unroll
      for (int m = 0; m < 4; m++)
#pragma unroll
        for (int n = 0; n < 4; n++)
          acc[m][n] = __builtin_amdgcn_mfma_f32_16x16x32_bf16(af[m], bfr[n], acc[m][n], 0, 0, 0);
    }
  }

  const int r4 = l4 * 4;
#pragma unroll
  for (int m = 0; m < 4; m++) {
#pragma unroll
    for (int n = 0; n < 4; n++) {
#pragma unroll
      for (int r = 0; r < 4; r++) {
        long grow = m0 + wm * 64 + m * 16 + r4 + r;
        long gcol = n0 + wn * 64 + n * 16 + l15;
        float v = acc[m][n][r];
        if constexpr (EPI == 0) {
          v += bias[gcol];
          int which = (int)(gcol >> 8);
          long jj = gcol & 255;
          if (which < 2) v = fmaxf(v, 0.f);
          u16 hv = f2b(v);
          if (which == 0) ob0[grow * 256 + jj] = hv;
          else if (which == 1) ob1[grow * 256 + jj] = hv;
          else ob2[grow * 256 + jj] = hv;
        } else if constexpr (EPI == 1) {
          v += bias[gcol];
          v = fmaxf(v, 0.f);
          ob0[grow * 256 + gcol] = f2b(v);
        } else if constexpr (EPI == 2) {
          ob0[grow * 65536 + gcol] = f2b(v * scale);
        } else {
          of[grow * 1024 + gcol] = v * scale;
        }
      }
    }
  }
}

// ---------------------------------------------------------------------------
// Weight prep: Wcat^T bf16 [768,256] rows = [wk cols | wv cols | wq cols]
// ---------------------------------------------------------------------------
__global__ __launch_bounds__(256)
void prep_w_kernel(const float* __restrict__ wq, const float* __restrict__ wk,
                   const float* __restrict__ wv, const float* __restrict__ bq,
                   const float* __restrict__ bk, const float* __restrict__ bv,
                   u16* __restrict__ wcat, float* __restrict__ bcat) {
  int n = blockIdx.x;
  int t = threadIdx.x;
  const float* W = (n < 256) ? wk : (n < 512) ? wv : wq;
  int jj = n & 255;
  wcat[n * 256 + t] = f2b(W[t * 256 + jj]);
  if (t == 0) {
    const float* Bb = (n < 256) ? bk : (n < 512) ? bv : bq;
    bcat[n] = Bb[jj];
  }
}

// ---------------------------------------------------------------------------
// x = LayerNorm(inputs) -> bf16.  One wave per row (4 f32 per lane).
// ---------------------------------------------------------------------------
__global__ __launch_bounds__(256)
void ln_x_kernel(const float* __restrict__ x, const float* __restrict__ lw,
                 const float* __restrict__ lb, u16* __restrict__ out) {
  const int lane = threadIdx.x & 63, wid = threadIdx.x >> 6;
  const long row = (long)blockIdx.x * 4 + wid;
  float4 v = reinterpret_cast<const float4*>(x + row * 256)[lane];
  float s = v.x + v.y + v.z + v.w;
  for (int sh = 1; sh < 64; sh <<= 1) s += __shfl_xor(s, sh);
  float mu = s * (1.f / 256.f);
  float dx = v.x - mu, dy = v.y - mu, dz = v.z - mu, dw = v.w - mu;
  float q = dx * dx + dy * dy + dz * dz + dw * dw;
  for (int sh = 1; sh < 64; sh <<= 1) q += __shfl_xor(q, sh);
  float rs = rsqrtf(q * (1.f / 256.f) + 1e-5f);
  float4 wv = reinterpret_cast<const float4*>(lw)[lane];
  float4 bv = reinterpret_cast<const float4*>(lb)[lane];
  ushort4 o4;
  o4.x = f2b(dx * rs * wv.x + bv.x);
  o4.y = f2b(dy * rs * wv.y + bv.y);
  o4.z = f2b(dz * rs * wv.z + bv.z);
  o4.w = f2b(dw * rs * wv.w + bv.w);
  reinterpret_cast<ushort4*>(out + row * 256)[lane] = o4;
}

// ---------------------------------------------------------------------------
// edges = mu + exp(ls)*noise ; e = LayerNorm(edges) -> f32 + bf16
// ---------------------------------------------------------------------------
__global__ __launch_bounds__(256)
void edges_e_kernel(const float* __restrict__ noise, const float* __restrict__ emu,
                    const float* __restrict__ els, const float* __restrict__ lw,
                    const float* __restrict__ lb, float* __restrict__ e_f,
                    u16* __restrict__ e_b) {
  const int lane = threadIdx.x & 63, wid = threadIdx.x >> 6;
  const long row = (long)blockIdx.x * 4 + wid;
  float4 nz = reinterpret_cast<const float4*>(noise + row * 256)[lane];
  float4 mu4 = reinterpret_cast<const float4*>(emu)[lane];
  float4 ls4 = reinterpret_cast<const float4*>(els)[lane];
  float4 ed;
  ed.x = mu4.x + expf(ls4.x) * nz.x;
  ed.y = mu4.y + expf(ls4.y) * nz.y;
  ed.z = mu4.z + expf(ls4.z) * nz.z;
  ed.w = mu4.w + expf(ls4.w) * nz.w;
  float s = ed.x + ed.y + ed.z + ed.w;
  for (int sh = 1; sh < 64; sh <<= 1) s += __shfl_xor(s, sh);
  float mu = s * (1.f / 256.f);
  float dx = ed.x - mu, dy = ed.y - mu, dz = ed.z - mu, dw = ed.w - mu;
  float qv = dx * dx + dy * dy + dz * dz + dw * dw;
  for (int sh = 1; sh < 64; sh <<= 1) qv += __shfl_xor(qv, sh);
  float rs = rsqrtf(qv * (1.f / 256.f) + 1e-5f);
  float4 wv = reinterpret_cast<const float4*>(lw)[lane];
  float4 bv = reinterpret_cast<const float4*>(lb)[lane];
  float4 ef;
  ef.x = dx * rs * wv.x + bv.x;
  ef.y = dy * rs * wv.y + bv.y;
  ef.z = dz * rs * wv.z + bv.z;
  ef.w = dw * rs * wv.w + bv.w;
  reinterpret_cast<float4*>(e_f + row * 256)[lane] = ef;
  ushort4 o4;
  o4.x = f2b(ef.x); o4.y = f2b(ef.y); o4.z = f2b(ef.z); o4.w = f2b(ef.w);
  reinterpret_cast<ushort4*>(e_b + row * 256)[lane] = o4;
}

// ---------------------------------------------------------------------------
// d2d3 v2 (unchanged): one block (256 threads) per q-row, ~27 KB LDS,
// all 1024 blocks co-resident.  3-pass streaming histogram rank-select
// + sparse attn@v gather.  Fixed softmax shift C=8.
// ---------------------------------------------------------------------------
struct D2Shm {
  u32 hist[256 * 16];     // 16 KiB: bin b, copy c at [b*16+c]
  u32 c_hi[256];
  u32 sel_idx[1152];
  float sel_w[1152];
  float fred[4];
  u32 sb_star, sThi, sThr;
  float sSE, sFrac;
  u32 scnt;
};

__global__ __launch_bounds__(256, 5)
void d2d3_kernel(const u16* __restrict__ dots, const u16* __restrict__ vmat,
                 const int* __restrict__ knp, float* __restrict__ upd) {
  __shared__ D2Shm S;
  const int tid = threadIdx.x, lane = tid & 63, wid = tid >> 6;
  const int hc = (lane >> 2);          // 16 lane-indexed histogram copies
  const long r = blockIdx.x;
  const int kn = *knp;

  for (int i = tid; i < 4096; i += 256) S.hist[i] = 0;
  if (tid == 0) S.scnt = 0;
  __syncthreads();

  const float C = 8.f;  // fixed softmax shift (dots >= 0 since q,k relu'd)
  const uint4* src = reinterpret_cast<const uint4*>(dots + r * 65536);

  // ---- pass 1: high-byte histogram + sum-exp ----
  float se = 0.f;
  for (int c = tid; c < 8192; c += 256) {
    uint4 d = src[c];
    u32 h[8] = {d.x & 0xffffu, d.x >> 16, d.y & 0xffffu, d.y >> 16,
                d.z & 0xffffu, d.z >> 16, d.w & 0xffffu, d.w >> 16};
#pragma unroll
    for (int j = 0; j < 8; j++) {
      u32 k = b2k(h[j]);
      se += __expf(b2f((u16)h[j]) - C);
      atomicAdd(&S.hist[(k >> 8) * 16 + hc], 1u);
    }
  }
  for (int sh = 1; sh < 64; sh <<= 1) se += __shfl_xor(se, sh);
  if (lane == 0) S.fred[wid] = se;
  __syncthreads();

  // reduce copies -> c_hi
  {
    u32 s = 0;
#pragma unroll
    for (int c = 0; c < 16; c++) s += S.hist[tid * 16 + c];
    S.c_hi[tid] = s;
  }
  __syncthreads();

  // ---- scan 1: wave 0 -> b*, Thi;  waves 1-3 re-zero hist ----
  if (tid < 64) {
    u32 s = S.c_hi[4 * tid] + S.c_hi[4 * tid + 1] + S.c_hi[4 * tid + 2] + S.c_hi[4 * tid + 3];
    u32 v = s;
    for (int off = 1; off < 64; off <<= 1) {
      u32 t = (u32)__shfl_down((int)v, off);
      if (tid + off < 64) v += t;        // inclusive suffix sum over lanes
    }
    u32 excl = v - s;
    if (v >= (u32)kn && excl < (u32)kn) {
      u32 acc = excl;
#pragma unroll
      for (int bb = 3; bb >= 0; --bb) {
        int b = 4 * tid + bb;
        u32 nb = acc + S.c_hi[b];
        if (nb >= (u32)kn) { S.sb_star = (u32)b; S.sThi = acc; break; }
        acc = nb;
      }
    }
  } else {
    for (int i = tid - 64; i < 4096; i += 192) S.hist[i] = 0;
  }
  __syncthreads();
  const u32 bstar = S.sb_star;

  // ---- pass 2: low-byte histogram within bin b* (row re-read, L3-hot) ----
  for (int c = tid; c < 8192; c += 256) {
    uint4 d = src[c];
    u32 h[8] = {d.x & 0xffffu, d.x >> 16, d.y & 0xffffu, d.y >> 16,
                d.z & 0xffffu, d.z >> 16, d.w & 0xffffu, d.w >> 16};
#pragma unroll
    for (int j = 0; j < 8; j++) {
      u32 k = b2k(h[j]);
      if ((k >> 8) == bstar) atomicAdd(&S.hist[(k & 255u) * 16 + hc], 1u);
    }
  }
  __syncthreads();
  {
    u32 s = 0;
#pragma unroll
    for (int c = 0; c < 16; c++) s += S.hist[tid * 16 + c];
    S.c_hi[tid] = s;
  }
  __syncthreads();

  // ---- scan 2: wave 0 -> exact threshold, tie counts, SE ----
  if (tid < 64) {
    u32 s = S.c_hi[4 * tid] + S.c_hi[4 * tid + 1] + S.c_hi[4 * tid + 2] + S.c_hi[4 * tid + 3];
    u32 v = s;
    for (int off = 1; off < 64; off <<= 1) {
      u32 t = (u32)__shfl_down((int)v, off);
      if (tid + off < 64) v += t;
    }
    const u32 Thi = S.sThi;              // count(high byte > b*)
    u32 incl = v + Thi;
    u32 excl = v - s + Thi;
    if (incl >= (u32)kn && excl < (u32)kn) {
      u32 acc = excl;
#pragma unroll
      for (int bb = 3; bb >= 0; --bb) {
        int b = 4 * tid + bb;
        u32 nb = acc + S.c_hi[b];
        if (nb >= (u32)kn) {
          S.sThr = (bstar << 8) | (u32)b;
          // acc = count(key > thr), c_hi[b] = count(key == thr)
          S.sFrac = (float)(int)((u32)kn - acc) / (float)S.c_hi[b];
          break;
        }
        acc = nb;
      }
    }
    if (tid == 0) {
      float SE = S.fred[0] + S.fred[1] + S.fred[2] + S.fred[3];
      S.sSE = SE;
    }
  }
  __syncthreads();
  const u32 thr = S.sThr;
  const float frac = S.sFrac;
  const float invs = 1.f / S.sSE;
  const float wnorm = 1.f / (1.f + 65536.f * 1e-8f);

  // ---- pass 3: selection: keys >= thr -> (global idx, weight) list ----
  for (int c = tid; c < 8192; c += 256) {
    uint4 d = src[c];
    u32 h[8] = {d.x & 0xffffu, d.x >> 16, d.y & 0xffffu, d.y >> 16,
                d.z & 0xffffu, d.z >> 16, d.w & 0xffffu, d.w >> 16};
#pragma unroll
    for (int j = 0; j < 8; j++) {
      u32 k = b2k(h[j]);
      if (k >= thr) {
        float w = (__expf(k2fv(k) - C) * invs + 1e-8f) * wnorm;
        if (k == thr) w *= frac;
        u32 p = atomicAdd(&S.scnt, 1u);
        if (p < 1152u) { S.sel_idx[p] = (u32)c * 8u + (u32)j; S.sel_w[p] = w; }
      }
    }
  }
  __syncthreads();
  const u32 nsel = S.scnt < 1152u ? S.scnt : 1152u;

  // ---- gather: thread t owns output col t; 4-deep ILP ----
  float a0 = 0.f, a1 = 0.f, a2 = 0.f, a3 = 0.f;
  u32 j = 0;
  for (; j + 3 < nsel; j += 4) {
    a0 = fmaf(S.sel_w[j], b2f(vmat[(long)S.sel_idx[j] * 256 + tid]), a0);
    a1 = fmaf(S.sel_w[j + 1], b2f(vmat[(long)S.sel_idx[j + 1] * 256 + tid]), a1);
    a2 = fmaf(S.sel_w[j + 2], b2f(vmat[(long)S.sel_idx[j + 2] * 256 + tid]), a2);
    a3 = fmaf(S.sel_w[j + 3], b2f(vmat[(long)S.sel_idx[j + 3] * 256 + tid]), a3);
  }
  for (; j < nsel; ++j)
    a0 = fmaf(S.sel_w[j], b2f(vmat[(long)S.sel_idx[j] * 256 + tid]), a0);
  upd[r * 256 + tid] = (a0 + a1) + (a2 + a3);
}

// ---------------------------------------------------------------------------
// mlp: edges_out = relu([e, upd] @ w1 + b1) @ w2 + b2   (f32, one block/row)
// ---------------------------------------------------------------------------
__global__ __launch_bounds__(256)
void mlp_kernel(const float* __restrict__ e, const float* __restrict__ upd,
                const float* __restrict__ w1, const float* __restrict__ b1,
                const float* __restrict__ w2, const float* __restrict__ b2,
                float* __restrict__ eout, u16* __restrict__ eb) {
  __shared__ float ecat[512];
  __shared__ float h[256];
  const int t = threadIdx.x;
  const long r = blockIdx.x;
  ecat[t] = e[r * 256 + t];
  ecat[256 + t] = upd[r * 256 + t];
  __syncthreads();
  float acc = b1[t];
#pragma unroll 8
  for (int kk = 0; kk < 512; ++kk) acc = fmaf(ecat[kk], w1[kk * 256 + t], acc);
  h[t] = fmaxf(acc, 0.f);
  __syncthreads();
  float a2 = b2[t];
#pragma unroll 8
  for (int kk = 0; kk < 256; ++kk) a2 = fmaf(h[kk], w2[kk * 256 + t], a2);
  eout[r * 256 + t] = a2;
  eb[r * 256 + t] = f2b(a2);
}

// ---------------------------------------------------------------------------
// g2 (split version): per row of dots2 [65536,1024]: softmax, top-ke mask,
// write H.  One wave per row, 16 f32/lane, 32-step binary search.
// ---------------------------------------------------------------------------
__global__ __launch_bounds__(256)
void g2_kernel(const float* __restrict__ d2, const int* __restrict__ kep,
               float* __restrict__ H) {
  const int lane = threadIdx.x & 63, wid = threadIdx.x >> 6;
  const long row = (long)blockIdx.x * 4 + wid;
  const int ke = *kep;
  const float4* src = reinterpret_cast<const float4*>(d2 + row * 1024);
  float4 q0 = src[lane], q1 = src[64 + lane], q2v = src[128 + lane], q3 = src[192 + lane];
  float x[16] = {q0.x, q0.y, q0.z, q0.w, q1.x, q1.y, q1.z, q1.w,
                 q2v.x, q2v.y, q2v.z, q2v.w, q3.x, q3.y, q3.z, q3.w};
  float mx = x[0];
#pragma unroll
  for (int i = 1; i < 16; i++) mx = fmaxf(mx, x[i]);
  for (int sh = 1; sh < 64; sh <<= 1) mx = fmaxf(mx, __shfl_xor(mx, sh));
  float p[16];
  float se = 0.f;
#pragma unroll
  for (int i = 0; i < 16; i++) { p[i] = __expf(x[i] - mx); se += p[i]; }
  for (int sh = 1; sh < 64; sh <<= 1) se += __shfl_xor(se, sh);
  const float invs = 1.f / se;
  u32 key[16];
#pragma unroll
  for (int i = 0; i < 16; i++) {
    u32 u = __builtin_bit_cast(u32, x[i]);
    key[i] = u ^ ((u >> 31) ? 0xFFFFFFFFu : 0x80000000u);
  }
  u32 lo = 0;
  for (int b = 31; b >= 0; --b) {
    u32 t = lo | (1u << b);
    int cnt = 0;
#pragma unroll
    for (int i = 0; i < 16; i++) cnt += (key[i] >= t);
    for (int sh = 1; sh < 64; sh <<= 1) cnt += __shfl_xor(cnt, sh);
    if (cnt >= ke) lo = t;
  }
  float4 o0, o1, o2, o3;
  o0.x = key[0] >= lo ? p[0] * invs : 0.f;
  o0.y = key[1] >= lo ? p[1] * invs : 0.f;
  o0.z = key[2] >= lo ? p[2] * invs : 0.f;
  o0.w = key[3] >= lo ? p[3] * invs : 0.f;
  o1.x = key[4] >= lo ? p[4] * invs : 0.f;
  o1.y = key[5] >= lo ? p[5] * invs : 0.f;
  o1.z = key[6] >= lo ? p[6] * invs : 0.f;
  o1.w = key[7] >= lo ? p[7] * invs : 0.f;
  o2.x = key[8] >= lo ? p[8] * invs : 0.f;
  o2.y = key[9] >= lo ? p[9] * invs : 0.f;
  o2.z = key[10] >= lo ? p[10] * invs : 0.f;
  o2.w = key[11] >= lo ? p[11] * invs : 0.f;
  o3.x = key[12] >= lo ? p[12] * invs : 0.f;
  o3.y = key[13] >= lo ? p[13] * invs : 0.f;
  o3.z = key[14] >= lo ? p[14] * invs : 0.f;
  o3.w = key[15] >= lo ? p[15] * invs : 0.f;
  float4* dst = reinterpret_cast<float4*>(H + row * 1024);
  dst[lane] = o0;
  dst[64 + lane] = o1;
  dst[128 + lane] = o2;
  dst[192 + lane] = o3;
}

// ---------------------------------------------------------------------------
extern "C" void kernel_launch(void* const* d_in, const int* in_sizes, int n_in,
                              void* d_out, int out_size, void* d_ws, size_t ws_size,
                              hipStream_t stream) {
  (void)in_sizes; (void)n_in; (void)out_size; (void)ws_size;

  float* out = (float*)d_out;
  float* out_edges = out;                       // [1024,256]
  float* out_H = out + NSL * DD;                // [65536,1024]
  float* out_d2 = out_H + NN * NSL;             // [65536,1024]

  // H region scratch (dead before g2 overwrites with H):
  char* Hb = (char*)out_H;
  u16* dots = (u16*)Hb;                          // 134217728 B
  u16* q2b = (u16*)(Hb + 134217728L);            // 32 MB
  char* smb = Hb + 167772160L;
  u16* wcat = (u16*)smb;      smb += 768 * 256 * 2;
  float* bcat = (float*)smb;  smb += 4096;
  float* e_f = (float*)smb;   smb += 1024 * 256 * 4;
  u16* e_b = (u16*)smb;       smb += 1024 * 256 * 2;
  u16* q_b = (u16*)smb;       smb += 1024 * 256 * 2;
  float* updf = (float*)smb;  smb += 1024 * 256 * 4;
  u16* edg_b = (u16*)smb;     smb += 1024 * 256 * 2;
  // dots2 region: xln, k, v bf16 (32MB each); dead before gemm<3> overwrites.
  char* Db = (char*)out_d2;
  u16* xln = (u16*)Db;
  u16* kb_ = (u16*)(Db + 33554432L);
  u16* vb_ = (u16*)(Db + 67108864L);
  // k2 in workspace (512 KB).
  u16* k2ws = (u16*)d_ws;

  prep_w_kernel<<<768, 256, 0, stream>>>(
      (const float*)d_in[4], (const float*)d_in[6], (const float*)d_in[8],
      (const float*)d_in[5], (const float*)d_in[7], (const float*)d_in[9], wcat, bcat);
  edges_e_kernel<<<256, 256, 0, stream>>>(
      (const float*)d_in[1], (const float*)d_in[2], (const float*)d_in[3],
      (const float*)d_in[16], (const float*)d_in[17], e_f, e_b);
  ln_x_kernel<<<16384, 256, 0, stream>>>(
      (const float*)d_in[0], (const float*)d_in[14], (const float*)d_in[15], xln);
  gemm_bt<1><<<dim3(2, 8), 256, 0, stream>>>(e_b, wcat + 512 * 256, bcat + 512, 1.f,
                                             q_b, nullptr, nullptr, nullptr);
  gemm_bt<0><<<dim3(6, 512), 256, 0, stream>>>(xln, wcat, bcat, 1.f,
                                               kb_, vb_, q2b, nullptr);
  gemm_bt<2><<<dim3(512, 8), 256, 0, stream>>>(q_b, kb_, nullptr, 0.0625f,
                                               dots, nullptr, nullptr, nullptr);
  d2d3_kernel<<<1024, 256, 0, stream>>>(dots, vb_, (const int*)d_in[18], updf);
  mlp_kernel<<<1024, 256, 0, stream>>>(e_f, updf,
                                       (const float*)d_in[10], (const float*)d_in[11],
                                       (const float*)d_in[12], (const float*)d_in[13],
                                       out_edges, edg_b);
  gemm_bt<1><<<dim3(2, 8), 256, 0, stream>>>(edg_b, wcat, bcat, 1.f,
                                             k2ws, nullptr, nullptr, nullptr);
  gemm_bt<3><<<dim3(8, 512), 256, 0, stream>>>(q2b, k2ws, nullptr, 0.0625f,
                                               nullptr, nullptr, nullptr, out_d2);
  g2_kernel<<<16384, 256, 0, stream>>>(out_d2, (const int*)d_in[19], out_H);
}

// Round 16
// 516.973 us; speedup vs baseline: 1.4476x; 1.1499x over previous
//
#include <hip/hip_runtime.h>
#include <hip/hip_bf16.h>
#include <stdint.h>

// ---------------------------------------------------------------------------
// HConstructor: slot-attention-like block on MI355X.
//   inputs [65536,256], noise [1024,256] -> edges [1024,256], H [65536,1024],
//   dots2 [65536,1024].
// Pipeline (all on `stream`):
//   prep_w   : Wcat^T = [wk|wv|wq]^T as bf16 [768,256], bias cat
//   edges_e  : edges = mu + exp(ls)*noise ; e = LN(edges)  (f32 + bf16)
//   ln_x     : x = LN(inputs) -> bf16 [65536,256]
//   gemm<1>  : q  = relu(e @ wq + bq)           [1024,256]  bf16
//   gemm<0>  : k,v = relu(x@wk/v + b), q2 = x@wq+bq (normal layout, H-region)
//   gemm<2>  : dots = (q @ k^T) * 1/16 -> bf16 [1024,65536] (H-region scratch)
//   d2d3 v3  : 3-pass streaming rank-select + VECTORIZED gather (R16: the
//              old gather was 2 B/lane loads -- 8x under-vectorized; now
//              4 groups x 64 threads x ushort4 = 8 B/lane, 2-deep ILP).
//   mlp      : edges_out = relu([e,upd]@w1+b1)@w2+b2 -> OUT + bf16
//   gemm<1>  : k2 = relu(edges_out @ wk + bk) -> d_ws (512 KB)
//   gemm<3>  : dots2 = (q2 @ k2^T) * 1/16 -> OUT f32       } SPLIT pair
//   g2 v2    : H = softmax(dots2) * top32-mask.  R16: 16-step search on
//              bf16-rounded keys (half the VALU of the 32-step f32 search;
//              semantics validated by R9-R13 fused version, absmax 0.008).
//
// LEDGER: rest=344 (X ~155 + d2d3 ~155), split=284; gemm staging uses
// global_load_lds width=16 with pre-swizzled global source (R15, -34us).
// Scratch map:
//   H region   : dots(134M) | q2b(32M) | smalls(~4M)   (dead before g2 -> H)
//   dots2 reg. : xln(32M) | kb(32M) | vb(32M)          (dead before gemm<3>)
//   d_ws       : k2 bf16 (512 KB)
// ---------------------------------------------------------------------------

#define DEV __device__ __forceinline__

typedef uint32_t u32;
typedef uint16_t u16;
typedef __bf16 v8bf __attribute__((ext_vector_type(8)));
typedef float v4f __attribute__((ext_vector_type(4)));

static constexpr long NN = 65536;
static constexpr long DD = 256;
static constexpr long NSL = 1024;

DEV u16 f2b(float f) {
  u32 u = __builtin_bit_cast(u32, f);
  u32 r = (u + 0x7FFFu + ((u >> 16) & 1u)) >> 16;
  return (u16)r;
}
DEV float b2f(u16 h) { u32 u = ((u32)h) << 16; return __builtin_bit_cast(float, u); }
// bf16 bits (as u32 low16) -> monotone sortable 16-bit key
DEV u32 b2k(u32 b) { return b ^ (0x8000u + 0x7FFFu * (b >> 15)); }
DEV float k2fv(u32 k) {
  u16 b = (k & 0x8000u) ? (u16)(k ^ 0x8000u) : (u16)(k ^ 0xFFFFu);
  return b2f(b);
}

// async global->LDS 16B copy: LDS dest must be wave-linear (base + lane*16).
DEV void gl_lds16(const u16* g, u16* l) {
  __builtin_amdgcn_global_load_lds(
      (const __attribute__((address_space(1))) u32*)g,
      (__attribute__((address_space(3))) u32*)l, 16, 0, 0);
}

// ---------------------------------------------------------------------------
// Generic  C[M,N] = epilogue(A[M,256] @ B[N,256]^T)   (bf16 in, MFMA 16x16x32)
// 128x128 tile, BK=64, 4 waves (2x2).  Staging via global_load_lds width=16:
// LDS layout linear in chunk id; the XOR swizzle (chunk ^ row&7) is applied
// on the GLOBAL SOURCE side (involution -> identical LDS contents; fragment
// reads unchanged).
// EPI 0: +biascat, relu for cols<512, route cols {0:k,1:v,2:q2} bf16 [M,256]
// EPI 1: +bias, relu, bf16 out [M,256]
// EPI 2: *scale, bf16 out ld=65536
// EPI 3: *scale, f32 out ld=1024
// ---------------------------------------------------------------------------
template <int EPI>
__global__ __launch_bounds__(256, 2)
void gemm_bt(const u16* __restrict__ A, const u16* __restrict__ B,
             const float* __restrict__ bias, float scale,
             u16* __restrict__ ob0, u16* __restrict__ ob1, u16* __restrict__ ob2,
             float* __restrict__ of) {
  __shared__ __align__(16) u16 As[128 * 64];
  __shared__ __align__(16) u16 Bs[128 * 64];
  const int tid = threadIdx.x;
  const int lane = tid & 63;
  const int l15 = lane & 15;
  const int l4 = lane >> 4;
  const int wid = tid >> 6;
  const int wm = wid >> 1, wn = wid & 1;
  const long m0 = (long)blockIdx.y * 128;
  const long n0 = (long)blockIdx.x * 128;

  v4f acc[4][4] = {};

  for (int kb = 0; kb < 256; kb += 64) {
    __syncthreads();
#pragma unroll
    for (int i = 0; i < 4; i++) {
      int cid = tid + 256 * i;          // 1024 16B-chunks per tile
      int row = cid >> 3, ch = cid & 7; // 8 chunks per 64-col row
      int sch = ch ^ (row & 7);         // pre-swizzled GLOBAL source chunk
      gl_lds16(A + (m0 + row) * 256 + kb + sch * 8, &As[cid * 8]);
      gl_lds16(B + (n0 + row) * 256 + kb + sch * 8, &Bs[cid * 8]);
    }
    __syncthreads();
#pragma unroll
    for (int ks = 0; ks < 2; ks++) {
      v8bf af[4], bfr[4];
#pragma unroll
      for (int m = 0; m < 4; m++) {
        int row = wm * 64 + m * 16 + l15;
        int sch = (ks * 4 + l4) ^ (row & 7);
        af[m] = *reinterpret_cast<const v8bf*>(&As[row * 64 + sch * 8]);
      }
#pragma unroll
      for (int n = 0; n < 4; n++) {
        int row = wn * 64 + n * 16 + l15;
        int sch = (ks * 4 + l4) ^ (row & 7);
        bfr[n] = *reinterpret_cast<const v8bf*>(&Bs[row * 64 + sch * 8]);
      }
#pragma unroll
      for (int m = 0; m < 4; m++)
#pragma unroll
        for (int n = 0; n < 4; n++)
          acc[m][n] = __builtin_amdgcn_mfma_f32_16x16x32_bf16(af[m], bfr[n], acc[m][n], 0, 0, 0);
    }
  }

  const int r4 = l4 * 4;
#pragma unroll
  for (int m = 0; m < 4; m++) {
#pragma unroll
    for (int n = 0; n < 4; n++) {
#pragma unroll
      for (int r = 0; r < 4; r++) {
        long grow = m0 + wm * 64 + m * 16 + r4 + r;
        long gcol = n0 + wn * 64 + n * 16 + l15;
        float v = acc[m][n][r];
        if constexpr (EPI == 0) {
          v += bias[gcol];
          int which = (int)(gcol >> 8);
          long jj = gcol & 255;
          if (which < 2) v = fmaxf(v, 0.f);
          u16 hv = f2b(v);
          if (which == 0) ob0[grow * 256 + jj] = hv;
          else if (which == 1) ob1[grow * 256 + jj] = hv;
          else ob2[grow * 256 + jj] = hv;
        } else if constexpr (EPI == 1) {
          v += bias[gcol];
          v = fmaxf(v, 0.f);
          ob0[grow * 256 + gcol] = f2b(v);
        } else if constexpr (EPI == 2) {
          ob0[grow * 65536 + gcol] = f2b(v * scale);
        } else {
          of[grow * 1024 + gcol] = v * scale;
        }
      }
    }
  }
}

// ---------------------------------------------------------------------------
// Weight prep: Wcat^T bf16 [768,256] rows = [wk cols | wv cols | wq cols]
// ---------------------------------------------------------------------------
__global__ __launch_bounds__(256)
void prep_w_kernel(const float* __restrict__ wq, const float* __restrict__ wk,
                   const float* __restrict__ wv, const float* __restrict__ bq,
                   const float* __restrict__ bk, const float* __restrict__ bv,
                   u16* __restrict__ wcat, float* __restrict__ bcat) {
  int n = blockIdx.x;
  int t = threadIdx.x;
  const float* W = (n < 256) ? wk : (n < 512) ? wv : wq;
  int jj = n & 255;
  wcat[n * 256 + t] = f2b(W[t * 256 + jj]);
  if (t == 0) {
    const float* Bb = (n < 256) ? bk : (n < 512) ? bv : bq;
    bcat[n] = Bb[jj];
  }
}

// ---------------------------------------------------------------------------
// x = LayerNorm(inputs) -> bf16.  One wave per row (4 f32 per lane).
// ---------------------------------------------------------------------------
__global__ __launch_bounds__(256)
void ln_x_kernel(const float* __restrict__ x, const float* __restrict__ lw,
                 const float* __restrict__ lb, u16* __restrict__ out) {
  const int lane = threadIdx.x & 63, wid = threadIdx.x >> 6;
  const long row = (long)blockIdx.x * 4 + wid;
  float4 v = reinterpret_cast<const float4*>(x + row * 256)[lane];
  float s = v.x + v.y + v.z + v.w;
  for (int sh = 1; sh < 64; sh <<= 1) s += __shfl_xor(s, sh);
  float mu = s * (1.f / 256.f);
  float dx = v.x - mu, dy = v.y - mu, dz = v.z - mu, dw = v.w - mu;
  float q = dx * dx + dy * dy + dz * dz + dw * dw;
  for (int sh = 1; sh < 64; sh <<= 1) q += __shfl_xor(q, sh);
  float rs = rsqrtf(q * (1.f / 256.f) + 1e-5f);
  float4 wv = reinterpret_cast<const float4*>(lw)[lane];
  float4 bv = reinterpret_cast<const float4*>(lb)[lane];
  ushort4 o4;
  o4.x = f2b(dx * rs * wv.x + bv.x);
  o4.y = f2b(dy * rs * wv.y + bv.y);
  o4.z = f2b(dz * rs * wv.z + bv.z);
  o4.w = f2b(dw * rs * wv.w + bv.w);
  reinterpret_cast<ushort4*>(out + row * 256)[lane] = o4;
}

// ---------------------------------------------------------------------------
// edges = mu + exp(ls)*noise ; e = LayerNorm(edges) -> f32 + bf16
// ---------------------------------------------------------------------------
__global__ __launch_bounds__(256)
void edges_e_kernel(const float* __restrict__ noise, const float* __restrict__ emu,
                    const float* __restrict__ els, const float* __restrict__ lw,
                    const float* __restrict__ lb, float* __restrict__ e_f,
                    u16* __restrict__ e_b) {
  const int lane = threadIdx.x & 63, wid = threadIdx.x >> 6;
  const long row = (long)blockIdx.x * 4 + wid;
  float4 nz = reinterpret_cast<const float4*>(noise + row * 256)[lane];
  float4 mu4 = reinterpret_cast<const float4*>(emu)[lane];
  float4 ls4 = reinterpret_cast<const float4*>(els)[lane];
  float4 ed;
  ed.x = mu4.x + expf(ls4.x) * nz.x;
  ed.y = mu4.y + expf(ls4.y) * nz.y;
  ed.z = mu4.z + expf(ls4.z) * nz.z;
  ed.w = mu4.w + expf(ls4.w) * nz.w;
  float s = ed.x + ed.y + ed.z + ed.w;
  for (int sh = 1; sh < 64; sh <<= 1) s += __shfl_xor(s, sh);
  float mu = s * (1.f / 256.f);
  float dx = ed.x - mu, dy = ed.y - mu, dz = ed.z - mu, dw = ed.w - mu;
  float qv = dx * dx + dy * dy + dz * dz + dw * dw;
  for (int sh = 1; sh < 64; sh <<= 1) qv += __shfl_xor(qv, sh);
  float rs = rsqrtf(qv * (1.f / 256.f) + 1e-5f);
  float4 wv = reinterpret_cast<const float4*>(lw)[lane];
  float4 bv = reinterpret_cast<const float4*>(lb)[lane];
  float4 ef;
  ef.x = dx * rs * wv.x + bv.x;
  ef.y = dy * rs * wv.y + bv.y;
  ef.z = dz * rs * wv.z + bv.z;
  ef.w = dw * rs * wv.w + bv.w;
  reinterpret_cast<float4*>(e_f + row * 256)[lane] = ef;
  ushort4 o4;
  o4.x = f2b(ef.x); o4.y = f2b(ef.y); o4.z = f2b(ef.z); o4.w = f2b(ef.w);
  reinterpret_cast<ushort4*>(e_b + row * 256)[lane] = o4;
}

// ---------------------------------------------------------------------------
// d2d3 v3: 3-pass streaming rank-select (unchanged) + vectorized gather:
// 4 groups x 64 threads, each thread owns 4 cols (ushort4 = 8 B/lane loads,
// was 2 B/lane), 2-deep index ILP; group partials reduced via dead hist LDS.
// ---------------------------------------------------------------------------
struct D2Shm {
  u32 hist[256 * 16];     // 16 KiB: bin b, copy c at [b*16+c]; gather reuses
  u32 c_hi[256];
  u32 sel_idx[1152];
  float sel_w[1152];
  float fred[4];
  u32 sb_star, sThi, sThr;
  float sSE, sFrac;
  u32 scnt;
};

__global__ __launch_bounds__(256, 5)
void d2d3_kernel(const u16* __restrict__ dots, const u16* __restrict__ vmat,
                 const int* __restrict__ knp, float* __restrict__ upd) {
  __shared__ D2Shm S;
  const int tid = threadIdx.x, lane = tid & 63, wid = tid >> 6;
  const int hc = (lane >> 2);          // 16 lane-indexed histogram copies
  const long r = blockIdx.x;
  const int kn = *knp;

  for (int i = tid; i < 4096; i += 256) S.hist[i] = 0;
  if (tid == 0) S.scnt = 0;
  __syncthreads();

  const float C = 8.f;  // fixed softmax shift (dots >= 0 since q,k relu'd)
  const uint4* src = reinterpret_cast<const uint4*>(dots + r * 65536);

  // ---- pass 1: high-byte histogram + sum-exp ----
  float se = 0.f;
  for (int c = tid; c < 8192; c += 256) {
    uint4 d = src[c];
    u32 h[8] = {d.x & 0xffffu, d.x >> 16, d.y & 0xffffu, d.y >> 16,
                d.z & 0xffffu, d.z >> 16, d.w & 0xffffu, d.w >> 16};
#pragma unroll
    for (int j = 0; j < 8; j++) {
      u32 k = b2k(h[j]);
      se += __expf(b2f((u16)h[j]) - C);
      atomicAdd(&S.hist[(k >> 8) * 16 + hc], 1u);
    }
  }
  for (int sh = 1; sh < 64; sh <<= 1) se += __shfl_xor(se, sh);
  if (lane == 0) S.fred[wid] = se;
  __syncthreads();

  // reduce copies -> c_hi
  {
    u32 s = 0;
#pragma unroll
    for (int c = 0; c < 16; c++) s += S.hist[tid * 16 + c];
    S.c_hi[tid] = s;
  }
  __syncthreads();

  // ---- scan 1: wave 0 -> b*, Thi;  waves 1-3 re-zero hist ----
  if (tid < 64) {
    u32 s = S.c_hi[4 * tid] + S.c_hi[4 * tid + 1] + S.c_hi[4 * tid + 2] + S.c_hi[4 * tid + 3];
    u32 v = s;
    for (int off = 1; off < 64; off <<= 1) {
      u32 t = (u32)__shfl_down((int)v, off);
      if (tid + off < 64) v += t;        // inclusive suffix sum over lanes
    }
    u32 excl = v - s;
    if (v >= (u32)kn && excl < (u32)kn) {
      u32 acc = excl;
#pragma unroll
      for (int bb = 3; bb >= 0; --bb) {
        int b = 4 * tid + bb;
        u32 nb = acc + S.c_hi[b];
        if (nb >= (u32)kn) { S.sb_star = (u32)b; S.sThi = acc; break; }
        acc = nb;
      }
    }
  } else {
    for (int i = tid - 64; i < 4096; i += 192) S.hist[i] = 0;
  }
  __syncthreads();
  const u32 bstar = S.sb_star;

  // ---- pass 2: low-byte histogram within bin b* (row re-read, L3-hot) ----
  for (int c = tid; c < 8192; c += 256) {
    uint4 d = src[c];
    u32 h[8] = {d.x & 0xffffu, d.x >> 16, d.y & 0xffffu, d.y >> 16,
                d.z & 0xffffu, d.z >> 16, d.w & 0xffffu, d.w >> 16};
#pragma unroll
    for (int j = 0; j < 8; j++) {
      u32 k = b2k(h[j]);
      if ((k >> 8) == bstar) atomicAdd(&S.hist[(k & 255u) * 16 + hc], 1u);
    }
  }
  __syncthreads();
  {
    u32 s = 0;
#pragma unroll
    for (int c = 0; c < 16; c++) s += S.hist[tid * 16 + c];
    S.c_hi[tid] = s;
  }
  __syncthreads();

  // ---- scan 2: wave 0 -> exact threshold, tie counts, SE ----
  if (tid < 64) {
    u32 s = S.c_hi[4 * tid] + S.c_hi[4 * tid + 1] + S.c_hi[4 * tid + 2] + S.c_hi[4 * tid + 3];
    u32 v = s;
    for (int off = 1; off < 64; off <<= 1) {
      u32 t = (u32)__shfl_down((int)v, off);
      if (tid + off < 64) v += t;
    }
    const u32 Thi = S.sThi;              // count(high byte > b*)
    u32 incl = v + Thi;
    u32 excl = v - s + Thi;
    if (incl >= (u32)kn && excl < (u32)kn) {
      u32 acc = excl;
#pragma unroll
      for (int bb = 3; bb >= 0; --bb) {
        int b = 4 * tid + bb;
        u32 nb = acc + S.c_hi[b];
        if (nb >= (u32)kn) {
          S.sThr = (bstar << 8) | (u32)b;
          // acc = count(key > thr), c_hi[b] = count(key == thr)
          S.sFrac = (float)(int)((u32)kn - acc) / (float)S.c_hi[b];
          break;
        }
        acc = nb;
      }
    }
    if (tid == 0) {
      float SE = S.fred[0] + S.fred[1] + S.fred[2] + S.fred[3];
      S.sSE = SE;
    }
  }
  __syncthreads();
  const u32 thr = S.sThr;
  const float frac = S.sFrac;
  const float invs = 1.f / S.sSE;
  const float wnorm = 1.f / (1.f + 65536.f * 1e-8f);

  // ---- pass 3: selection: keys >= thr -> (global idx, weight) list ----
  for (int c = tid; c < 8192; c += 256) {
    uint4 d = src[c];
    u32 h[8] = {d.x & 0xffffu, d.x >> 16, d.y & 0xffffu, d.y >> 16,
                d.z & 0xffffu, d.z >> 16, d.w & 0xffffu, d.w >> 16};
#pragma unroll
    for (int j = 0; j < 8; j++) {
      u32 k = b2k(h[j]);
      if (k >= thr) {
        float w = (__expf(k2fv(k) - C) * invs + 1e-8f) * wnorm;
        if (k == thr) w *= frac;
        u32 p = atomicAdd(&S.scnt, 1u);
        if (p < 1152u) { S.sel_idx[p] = (u32)c * 8u + (u32)j; S.sel_w[p] = w; }
      }
    }
  }
  __syncthreads();
  const u32 nsel = S.scnt < 1152u ? S.scnt : 1152u;

  // ---- gather v2: 4 groups x 64 threads, 4 cols/thread (ushort4 loads) ----
  const int g = tid >> 6;              // group = wid
  const int c0 = (tid & 63) * 4;       // col base
  float a0 = 0.f, a1 = 0.f, a2 = 0.f, a3 = 0.f;
  float b0 = 0.f, b1 = 0.f, b2 = 0.f, b3 = 0.f;
  u32 j = (u32)g;
  for (; j + 4 < nsel; j += 8) {
    u32 i0 = S.sel_idx[j];      float w0 = S.sel_w[j];
    u32 i1 = S.sel_idx[j + 4];  float w1 = S.sel_w[j + 4];
    ushort4 v0 = *reinterpret_cast<const ushort4*>(vmat + (long)i0 * 256 + c0);
    ushort4 v1 = *reinterpret_cast<const ushort4*>(vmat + (long)i1 * 256 + c0);
    a0 = fmaf(w0, b2f(v0.x), a0); a1 = fmaf(w0, b2f(v0.y), a1);
    a2 = fmaf(w0, b2f(v0.z), a2); a3 = fmaf(w0, b2f(v0.w), a3);
    b0 = fmaf(w1, b2f(v1.x), b0); b1 = fmaf(w1, b2f(v1.y), b1);
    b2 = fmaf(w1, b2f(v1.z), b2); b3 = fmaf(w1, b2f(v1.w), b3);
  }
  for (; j < nsel; j += 4) {
    u32 i0 = S.sel_idx[j];  float w0 = S.sel_w[j];
    ushort4 v0 = *reinterpret_cast<const ushort4*>(vmat + (long)i0 * 256 + c0);
    a0 = fmaf(w0, b2f(v0.x), a0); a1 = fmaf(w0, b2f(v0.y), a1);
    a2 = fmaf(w0, b2f(v0.z), a2); a3 = fmaf(w0, b2f(v0.w), a3);
  }
  __syncthreads();                     // hist no longer needed -> partials
  float* part = reinterpret_cast<float*>(S.hist);
  float4 pv;
  pv.x = a0 + b0; pv.y = a1 + b1; pv.z = a2 + b2; pv.w = a3 + b3;
  *reinterpret_cast<float4*>(&part[g * 256 + c0]) = pv;
  __syncthreads();
  upd[r * 256 + tid] = part[tid] + part[256 + tid] + part[512 + tid] + part[768 + tid];
}

// ---------------------------------------------------------------------------
// mlp: edges_out = relu([e, upd] @ w1 + b1) @ w2 + b2   (f32, one block/row)
// ---------------------------------------------------------------------------
__global__ __launch_bounds__(256)
void mlp_kernel(const float* __restrict__ e, const float* __restrict__ upd,
                const float* __restrict__ w1, const float* __restrict__ b1,
                const float* __restrict__ w2, const float* __restrict__ b2,
                float* __restrict__ eout, u16* __restrict__ eb) {
  __shared__ float ecat[512];
  __shared__ float h[256];
  const int t = threadIdx.x;
  const long r = blockIdx.x;
  ecat[t] = e[r * 256 + t];
  ecat[256 + t] = upd[r * 256 + t];
  __syncthreads();
  float acc = b1[t];
#pragma unroll 8
  for (int kk = 0; kk < 512; ++kk) acc = fmaf(ecat[kk], w1[kk * 256 + t], acc);
  h[t] = fmaxf(acc, 0.f);
  __syncthreads();
  float a2 = b2[t];
#pragma unroll 8
  for (int kk = 0; kk < 256; ++kk) a2 = fmaf(h[kk], w2[kk * 256 + t], a2);
  eout[r * 256 + t] = a2;
  eb[r * 256 + t] = f2b(a2);
}

// ---------------------------------------------------------------------------
// g2 v2: per row of dots2 [65536,1024]: softmax, top-ke mask, write H.
// One wave per row, 16 f32/lane.  Rank search on bf16-ROUNDED keys
// (16 steps, half the VALU; semantics validated by R9-R13 fused version).
// H values themselves stay f32-precise.
// ---------------------------------------------------------------------------
__global__ __launch_bounds__(256)
void g2_kernel(const float* __restrict__ d2, const int* __restrict__ kep,
               float* __restrict__ H) {
  const int lane = threadIdx.x & 63, wid = threadIdx.x >> 6;
  const long row = (long)blockIdx.x * 4 + wid;
  const int ke = *kep;
  const float4* src = reinterpret_cast<const float4*>(d2 + row * 1024);
  float4 q0 = src[lane], q1 = src[64 + lane], q2v = src[128 + lane], q3 = src[192 + lane];
  float x[16] = {q0.x, q0.y, q0.z, q0.w, q1.x, q1.y, q1.z, q1.w,
                 q2v.x, q2v.y, q2v.z, q2v.w, q3.x, q3.y, q3.z, q3.w};
  float mx = x[0];
#pragma unroll
  for (int i = 1; i < 16; i++) mx = fmaxf(mx, x[i]);
  for (int sh = 1; sh < 64; sh <<= 1) mx = fmaxf(mx, __shfl_xor(mx, sh));
  float p[16];
  float se = 0.f;
#pragma unroll
  for (int i = 0; i < 16; i++) { p[i] = __expf(x[i] - mx); se += p[i]; }
  for (int sh = 1; sh < 64; sh <<= 1) se += __shfl_xor(se, sh);
  const float invs = 1.f / se;
  u32 key[16];
#pragma unroll
  for (int i = 0; i < 16; i++) key[i] = b2k((u32)f2b(x[i]));
  u32 lo = 0;
  for (int b = 15; b >= 0; --b) {
    u32 t = lo | (1u << b);
    int cnt = 0;
#pragma unroll
    for (int i = 0; i < 16; i++) cnt += (key[i] >= t);
    for (int sh = 1; sh < 64; sh <<= 1) cnt += __shfl_xor(cnt, sh);
    if (cnt >= ke) lo = t;
  }
  float4 o0, o1, o2, o3;
  o0.x = key[0] >= lo ? p[0] * invs : 0.f;
  o0.y = key[1] >= lo ? p[1] * invs : 0.f;
  o0.z = key[2] >= lo ? p[2] * invs : 0.f;
  o0.w = key[3] >= lo ? p[3] * invs : 0.f;
  o1.x = key[4] >= lo ? p[4] * invs : 0.f;
  o1.y = key[5] >= lo ? p[5] * invs : 0.f;
  o1.z = key[6] >= lo ? p[6] * invs : 0.f;
  o1.w = key[7] >= lo ? p[7] * invs : 0.f;
  o2.x = key[8] >= lo ? p[8] * invs : 0.f;
  o2.y = key[9] >= lo ? p[9] * invs : 0.f;
  o2.z = key[10] >= lo ? p[10] * invs : 0.f;
  o2.w = key[11] >= lo ? p[11] * invs : 0.f;
  o3.x = key[12] >= lo ? p[12] * invs : 0.f;
  o3.y = key[13] >= lo ? p[13] * invs : 0.f;
  o3.z = key[14] >= lo ? p[14] * invs : 0.f;
  o3.w = key[15] >= lo ? p[15] * invs : 0.f;
  float4* dst = reinterpret_cast<float4*>(H + row * 1024);
  dst[lane] = o0;
  dst[64 + lane] = o1;
  dst[128 + lane] = o2;
  dst[192 + lane] = o3;
}

// ---------------------------------------------------------------------------
extern "C" void kernel_launch(void* const* d_in, const int* in_sizes, int n_in,
                              void* d_out, int out_size, void* d_ws, size_t ws_size,
                              hipStream_t stream) {
  (void)in_sizes; (void)n_in; (void)out_size; (void)ws_size;

  float* out = (float*)d_out;
  float* out_edges = out;                       // [1024,256]
  float* out_H = out + NSL * DD;                // [65536,1024]
  float* out_d2 = out_H + NN * NSL;             // [65536,1024]

  // H region scratch (dead before g2 overwrites with H):
  char* Hb = (char*)out_H;
  u16* dots = (u16*)Hb;                          // 134217728 B
  u16* q2b = (u16*)(Hb + 134217728L);            // 32 MB
  char* smb = Hb + 167772160L;
  u16* wcat = (u16*)smb;      smb += 768 * 256 * 2;
  float* bcat = (float*)smb;  smb += 4096;
  float* e_f = (float*)smb;   smb += 1024 * 256 * 4;
  u16* e_b = (u16*)smb;       smb += 1024 * 256 * 2;
  u16* q_b = (u16*)smb;       smb += 1024 * 256 * 2;
  float* updf = (float*)smb;  smb += 1024 * 256 * 4;
  u16* edg_b = (u16*)smb;     smb += 1024 * 256 * 2;
  // dots2 region: xln, k, v bf16 (32MB each); dead before gemm<3> overwrites.
  char* Db = (char*)out_d2;
  u16* xln = (u16*)Db;
  u16* kb_ = (u16*)(Db + 33554432L);
  u16* vb_ = (u16*)(Db + 67108864L);
  // k2 in workspace (512 KB).
  u16* k2ws = (u16*)d_ws;

  prep_w_kernel<<<768, 256, 0, stream>>>(
      (const float*)d_in[4], (const float*)d_in[6], (const float*)d_in[8],
      (const float*)d_in[5], (const float*)d_in[7], (const float*)d_in[9], wcat, bcat);
  edges_e_kernel<<<256, 256, 0, stream>>>(
      (const float*)d_in[1], (const float*)d_in[2], (const float*)d_in[3],
      (const float*)d_in[16], (const float*)d_in[17], e_f, e_b);
  ln_x_kernel<<<16384, 256, 0, stream>>>(
      (const float*)d_in[0], (const float*)d_in[14], (const float*)d_in[15], xln);
  gemm_bt<1><<<dim3(2, 8), 256, 0, stream>>>(e_b, wcat + 512 * 256, bcat + 512, 1.f,
                                             q_b, nullptr, nullptr, nullptr);
  gemm_bt<0><<<dim3(6, 512), 256, 0, stream>>>(xln, wcat, bcat, 1.f,
                                               kb_, vb_, q2b, nullptr);
  gemm_bt<2><<<dim3(512, 8), 256, 0, stream>>>(q_b, kb_, nullptr, 0.0625f,
                                               dots, nullptr, nullptr, nullptr);
  d2d3_kernel<<<1024, 256, 0, stream>>>(dots, vb_, (const int*)d_in[18], updf);
  mlp_kernel<<<1024, 256, 0, stream>>>(e_f, updf,
                                       (const float*)d_in[10], (const float*)d_in[11],
                                       (const float*)d_in[12], (const float*)d_in[13],
                                       out_edges, edg_b);
  gemm_bt<1><<<dim3(2, 8), 256, 0, stream>>>(edg_b, wcat, bcat, 1.f,
                                             k2ws, nullptr, nullptr, nullptr);
  gemm_bt<3><<<dim3(8, 512), 256, 0, stream>>>(q2b, k2ws, nullptr, 0.0625f,
                                               nullptr, nullptr, nullptr, out_d2);
  g2_kernel<<<16384, 256, 0, stream>>>(out_d2, (const int*)d_in[19], out_H);
}